// Round 10
// baseline (744.045 us; speedup 1.0000x reference)
//
#include <hip/hip_runtime.h>

typedef unsigned int uint;
typedef unsigned short ushort;
typedef uint4 uint4_a __attribute__((may_alias));
typedef uint ui4v __attribute__((ext_vector_type(4)));
typedef float fx4 __attribute__((ext_vector_type(4)));
typedef short s8v __attribute__((ext_vector_type(8)));

// ---------- bf16 helpers ----------
__device__ __forceinline__ uint bfpack(float a, float b) {
  uint ua = __float_as_uint(a), ub = __float_as_uint(b);
  ua += 0x7fffu + ((ua >> 16) & 1u);   // RNE
  ub += 0x7fffu + ((ub >> 16) & 1u);
  return (ua >> 16) | (ub & 0xffff0000u);
}
__device__ __forceinline__ float bflo(uint d) { return __uint_as_float(d << 16); }
__device__ __forceinline__ float bfhi(uint d) { return __uint_as_float(d & 0xffff0000u); }
__device__ __forceinline__ ushort bfr(float s) {          // round-half-up f32->bf16
  return (ushort)((__float_as_uint(s) + 0x8000u) >> 16);
}

#if __has_builtin(__builtin_amdgcn_fdot2_f32_bf16)
#define HAVE_BFDOT 1
typedef __bf16 v2bf __attribute__((ext_vector_type(2)));
__device__ __forceinline__ float dot2bf(uint a, uint b, float c) {
  return __builtin_amdgcn_fdot2_f32_bf16(__builtin_bit_cast(v2bf, a),
                                         __builtin_bit_cast(v2bf, b), c, false);
}
#else
#define HAVE_BFDOT 0
#endif

// ---------- K1: transition table, column-pair layout ----------
// Tcol[c*64 + kp] = bf16x2( exp(tran[2kp][c]), exp(tran[2kp+1][c]) )
__global__ void k_tran(const float* __restrict__ w, uint* __restrict__ Tcol) {
  __shared__ float rowLSE[128];
  int tid = threadIdx.x;                       // 128 threads
  const float4* w4 = (const float4*)(w + tid * 128);
  float se = 0.f;
  #pragma unroll 8
  for (int i = 0; i < 32; ++i) {
    float4 v = w4[i];
    se += __expf(v.x) + __expf(v.y) + __expf(v.z) + __expf(v.w);
  }
  rowLSE[tid] = __logf(se);
  __syncthreads();
  int c = tid;
  for (int j = 0; j < 64; ++j) {
    float a = __expf(w[(2 * j) * 128 + c]     - rowLSE[2 * j]);
    float b = __expf(w[(2 * j + 1) * 128 + c] - rowLSE[2 * j + 1]);
    Tcol[c * 64 + j] = bfpack(a, b);
  }
}

// ---------- K2a: logits (bf16, pair layout) + per-k sum of exp(logit) ----------
__global__ __launch_bounds__(256) void k_logits(const float* __restrict__ emb,
    const float* __restrict__ vocab, uint* __restrict__ qtbl,
    float* __restrict__ S_glob, int V) {
  __shared__ float S_part[128];
  int tid = threadIdx.x;
  int kt = tid & 15, vt = tid >> 4;
  int k0 = kt * 8;
  int vbase = blockIdx.x * 64 + vt * 4;
  if (tid < 128) S_part[tid] = 0.f;
  __syncthreads();

  float acc[4][8];
  #pragma unroll
  for (int i = 0; i < 4; ++i)
    #pragma unroll
    for (int r = 0; r < 8; ++r) acc[i][r] = 0.f;

  int vidx[4];
  #pragma unroll
  for (int i = 0; i < 4; ++i) { int vv = vbase + i; vidx[i] = (vv < V) ? vv : (V - 1); }

  const float4* emb4 = (const float4*)emb;
  const float4* voc4 = (const float4*)vocab;
  for (int jb = 0; jb < 32; ++jb) {
    float4 e4[8];
    #pragma unroll
    for (int r = 0; r < 8; ++r) e4[r] = emb4[(k0 + r) * 32 + jb];
    #pragma unroll
    for (int i = 0; i < 4; ++i) {
      float4 va = voc4[(size_t)vidx[i] * 32 + jb];
      #pragma unroll
      for (int r = 0; r < 8; ++r)
        acc[i][r] += va.x * e4[r].x + va.y * e4[r].y + va.z * e4[r].z + va.w * e4[r].w;
    }
  }

  float sume[8];
  #pragma unroll
  for (int r = 0; r < 8; ++r) sume[r] = 0.f;
  #pragma unroll
  for (int i = 0; i < 4; ++i) {
    int vv = vbase + i;
    if (vv < V) {
      #pragma unroll
      for (int r = 0; r < 8; ++r) sume[r] += __expf(acc[i][r]);
      uint4 st;
      st.x = bfpack(acc[i][0], acc[i][1]);
      st.y = bfpack(acc[i][2], acc[i][3]);
      st.z = bfpack(acc[i][4], acc[i][5]);
      st.w = bfpack(acc[i][6], acc[i][7]);
      *((uint4*)(qtbl + (size_t)vv * 64) + kt) = st;
    }
  }
  #pragma unroll
  for (int r = 0; r < 8; ++r) atomicAdd(&S_part[k0 + r], sume[r]);
  __syncthreads();
  if (tid < 128) atomicAdd(&S_glob[tid], S_part[tid]);
}

// ---------- K2c: in-place q[v][k] = exp(emis - Emax_v) (bf16), Emax table ----------
__global__ __launch_bounds__(256) void k_qtab(uint* __restrict__ qtbl,
    const float* __restrict__ S_glob, float* __restrict__ Emax, int V) {
  int tid = threadIdx.x;
  int l = tid & 63;
  int v = blockIdx.x * 4 + (tid >> 6);
  if (v >= V) return;
  float2 S2 = ((const float2*)S_glob)[l];
  float z0 = __logf(S2.x), z1 = __logf(S2.y);
  size_t off = (size_t)v * 64 + l;
  uint d = qtbl[off];
  float e0 = bflo(d) - z0, e1 = bfhi(d) - z1;
  float m = fmaxf(e0, e1);
  #pragma unroll
  for (int s = 1; s < 64; s <<= 1) m = fmaxf(m, __shfl_xor(m, s, 64));
  float q0 = __expf(e0 - m), q1 = __expf(e1 - m);
  qtbl[off] = bfpack(q0, q1);
  if (l == 0) Emax[v] = m;
}

// =====================================================================
// PHASE 1 (S-form, register-resident, SPLIT-SEGMENT): per (chain,
// segment) compute P_seg = prod_t (T D_t) via S <- D_t (T^T S).
// S-COLUMNS ARE INDEPENDENT (the fold couples rows, not columns), so a
// segment is split across TWO 4-wave blocks: block half h owns columns
// [64h, 64h+64); wave wv within it owns columns [16(4h+wv), +16).
// With 512 blocks at 2 blocks/CU, the 2 waves/SIMD come from DIFFERENT
// blocks/segments -> de-correlated load/latency timelines (tests the
// R9 lock-step theory for the ~50% MFMA-pipe idle).  Per-wave code,
// registers, and math are bit-identical to R9 (wv -> gw=4h+wv only).
// T^T fragments static in AGPRs; relabeled k-order so each lane's MFMA
// C-output IS its own next-fold B-fragment after scale+cvt_pk (zero
// LDS/cross-lane).  Stage-pipelined slots; rescale every 4th fold
// (guarded); per-column log-scales -> LLseg[seg*128 + row].
// =====================================================================
#define REPB(M) M(0,0) M(0,1) M(0,2) M(0,3) M(1,0) M(1,1) M(1,2) M(1,3) \
                M(2,0) M(2,1) M(2,2) M(2,3) M(3,0) M(3,1) M(3,2) M(3,3) \
                M(4,0) M(4,1) M(4,2) M(4,3) M(5,0) M(5,1) M(5,2) M(5,3) \
                M(6,0) M(6,1) M(6,2) M(6,3) M(7,0) M(7,1) M(7,2) M(7,3)

#define MFMA(a, b, c) __builtin_amdgcn_mfma_f32_16x16x32_bf16( \
    __builtin_bit_cast(s8v, a), __builtin_bit_cast(s8v, b), c, 0, 0, 0)

// stage-0: 8 independent MFMAs, C from zero
#define MST0(OUT, BN) \
  OUT##0 = MFMA(tb0_0, BN, zz4); OUT##1 = MFMA(tb1_0, BN, zz4); \
  OUT##2 = MFMA(tb2_0, BN, zz4); OUT##3 = MFMA(tb3_0, BN, zz4); \
  OUT##4 = MFMA(tb4_0, BN, zz4); OUT##5 = MFMA(tb5_0, BN, zz4); \
  OUT##6 = MFMA(tb6_0, BN, zz4); OUT##7 = MFMA(tb7_0, BN, zz4);
// stage-ks accumulate
#define MSTA(OUT, BN, ks) \
  OUT##0 = MFMA(tb0_##ks, BN, OUT##0); OUT##1 = MFMA(tb1_##ks, BN, OUT##1); \
  OUT##2 = MFMA(tb2_##ks, BN, OUT##2); OUT##3 = MFMA(tb3_##ks, BN, OUT##3); \
  OUT##4 = MFMA(tb4_##ks, BN, OUT##4); OUT##5 = MFMA(tb5_##ks, BN, OUT##5); \
  OUT##6 = MFMA(tb6_##ks, BN, OUT##6); OUT##7 = MFMA(tb7_##ks, BN, OUT##7);

// rescale pack: B = cvt_pk(cc*(q*rs)), track fm
#define PKPAIR(CCA, CCB, QA, QB, DOUT) { \
  float f0 = bflo(QA.x) * rs, f1 = bfhi(QA.x) * rs; \
  float f2 = bflo(QA.y) * rs, f3 = bfhi(QA.y) * rs; \
  float s0 = CCA.x * f0, s1 = CCA.y * f1, s2 = CCA.z * f2, s3 = CCA.w * f3; \
  fm = fmaxf(fm, fmaxf(fmaxf(s0, s1), fmaxf(s2, s3))); \
  uint p0, p1, p2, p3; \
  asm("v_cvt_pk_bf16_f32 %0, %1, %2" : "=v"(p0) : "v"(s0), "v"(s1)); \
  asm("v_cvt_pk_bf16_f32 %0, %1, %2" : "=v"(p1) : "v"(s2), "v"(s3)); \
  float g0 = bflo(QB.x) * rs, g1 = bfhi(QB.x) * rs; \
  float g2 = bflo(QB.y) * rs, g3 = bfhi(QB.y) * rs; \
  float t0 = CCB.x * g0, t1 = CCB.y * g1, t2 = CCB.z * g2, t3 = CCB.w * g3; \
  fm = fmaxf(fm, fmaxf(fmaxf(t0, t1), fmaxf(t2, t3))); \
  asm("v_cvt_pk_bf16_f32 %0, %1, %2" : "=v"(p2) : "v"(t0), "v"(t1)); \
  asm("v_cvt_pk_bf16_f32 %0, %1, %2" : "=v"(p3) : "v"(t2), "v"(t3)); \
  DOUT.x = p0; DOUT.y = p1; DOUT.z = p2; DOUT.w = p3; }

// plain pack: B = cvt_pk(cc*q)
#define PKPAIR_NR(CCA, CCB, QA, QB, DOUT) { \
  float s0 = CCA.x * bflo(QA.x), s1 = CCA.y * bfhi(QA.x); \
  float s2 = CCA.z * bflo(QA.y), s3 = CCA.w * bfhi(QA.y); \
  uint p0, p1, p2, p3; \
  asm("v_cvt_pk_bf16_f32 %0, %1, %2" : "=v"(p0) : "v"(s0), "v"(s1)); \
  asm("v_cvt_pk_bf16_f32 %0, %1, %2" : "=v"(p1) : "v"(s2), "v"(s3)); \
  float t0 = CCB.x * bflo(QB.x), t1 = CCB.y * bfhi(QB.x); \
  float t2 = CCB.z * bflo(QB.y), t3 = CCB.w * bfhi(QB.y); \
  asm("v_cvt_pk_bf16_f32 %0, %1, %2" : "=v"(p2) : "v"(t0), "v"(t1)); \
  asm("v_cvt_pk_bf16_f32 %0, %1, %2" : "=v"(p3) : "v"(t2), "v"(t3)); \
  DOUT.x = p0; DOUT.y = p1; DOUT.z = p2; DOUT.w = p3; }

#define QLD(dst, tk, i) dst = *(const uint2*)(qtbl + ((size_t)(tk) << 6) + 8 * (i) + 2 * quad);

#define QRELOAD(Q, TKREG, FBASE) \
  QLD(Q##0, TKREG, 0) QLD(Q##1, TKREG, 1) QLD(Q##2, TKREG, 2) QLD(Q##3, TKREG, 3) \
  QLD(Q##4, TKREG, 4) QLD(Q##5, TKREG, 5) QLD(Q##6, TKREG, 6) QLD(Q##7, TKREG, 7) \
  { int fi_ = (FBASE) + 4; if (fi_ > 511) fi_ = 511; TKREG = xseg[fi_]; }

// pipelined slot: fold f's PKPAIRs (CIN -> Bs) interleaved with fold
// f+1's MFMA stages (Bs -> COUT).  RS variant tracks/applies rescale.
#define SLOT_RS(CIN, COUT, Q, TKREG, FBASE) { \
  rs = 1.0f / fmA;  llacc += __log2f(fmA); \
  float fm = 0.f; \
  PKPAIR(CIN##0, CIN##1, Q##0, Q##1, Bs0) \
  MST0(COUT, Bs0) \
  PKPAIR(CIN##2, CIN##3, Q##2, Q##3, Bs1) \
  MSTA(COUT, Bs1, 1) \
  PKPAIR(CIN##4, CIN##5, Q##4, Q##5, Bs2) \
  MSTA(COUT, Bs2, 2) \
  PKPAIR(CIN##6, CIN##7, Q##6, Q##7, Bs3) \
  MSTA(COUT, Bs3, 3) \
  QRELOAD(Q, TKREG, FBASE) \
  fm = fmaxf(fm, __shfl_xor(fm, 16, 64)); \
  fm = fmaxf(fm, __shfl_xor(fm, 32, 64)); \
  fmA = fmaxf(fm, 1e-33f); \
}

#define SLOT_NR(CIN, COUT, Q, TKREG, FBASE) { \
  PKPAIR_NR(CIN##0, CIN##1, Q##0, Q##1, Bs0) \
  MST0(COUT, Bs0) \
  PKPAIR_NR(CIN##2, CIN##3, Q##2, Q##3, Bs1) \
  MSTA(COUT, Bs1, 1) \
  PKPAIR_NR(CIN##4, CIN##5, Q##4, Q##5, Bs2) \
  MSTA(COUT, Bs2, 2) \
  PKPAIR_NR(CIN##6, CIN##7, Q##6, Q##7, Bs3) \
  MSTA(COUT, Bs3, 3) \
  QRELOAD(Q, TKREG, FBASE) \
}

__global__ __attribute__((amdgpu_flat_work_group_size(256, 256), amdgpu_waves_per_eu(2)))
void k_seg(const int* __restrict__ x, const uint* __restrict__ Tcol,
           const uint* __restrict__ qtbl, uint* __restrict__ Pst,
           float* __restrict__ LLseg) {
  int tid = threadIdx.x;
  int wv = tid >> 6, l = tid & 63, c = l & 15, quad = l >> 4;
  int blk = blockIdx.x;
  int seg = blk >> 1, half = blk & 1;
  int gw = 4 * half + wv;                 // global wave index 0..7 (column strip)
  const int* xseg = x + (size_t)(seg >> 3) * 4096 + (size_t)(seg & 7) * 512;

  // A-frags (T^T, relabeled k-order) -> AGPRs.
  #define DECLB(nt, ks) ui4v tb##nt##_##ks;
  REPB(DECLB)
  {
    #define LOADB(nt, ks) { \
      const uint2* t2_ = (const uint2*)(Tcol + (size_t)(16 * (nt) + c) * 64 + 16 * (ks) + 2 * quad); \
      uint2 lo_ = t2_[0], hi_ = t2_[4]; \
      tb##nt##_##ks.x = lo_.x; tb##nt##_##ks.y = lo_.y; \
      tb##nt##_##ks.z = hi_.x; tb##nt##_##ks.w = hi_.y; }
    REPB(LOADB)
    #define PINB(nt, ks) asm volatile("" : "+a"(tb##nt##_##ks));
    REPB(PINB)
  }

  // B-frag staging regs (persistent; slot 3 of the last iteration
  // leaves the FINAL state here).  Identity init for fold 0:
  // col 16gw+c has its 1.0 at k = 16gw+c.
  ui4v Bs0, Bs1, Bs2, Bs3;
  {
    uint iv = (quad == (c >> 2)) ? (0x3F80u << (16 * (c & 1))) : 0u;
    int dsel = ((c >> 1) & 1) + 2 * (gw & 1);
    int kssel = gw >> 1;
    Bs0.x = (kssel == 0 && dsel == 0) ? iv : 0u;
    Bs0.y = (kssel == 0 && dsel == 1) ? iv : 0u;
    Bs0.z = (kssel == 0 && dsel == 2) ? iv : 0u;
    Bs0.w = (kssel == 0 && dsel == 3) ? iv : 0u;
    Bs1.x = (kssel == 1 && dsel == 0) ? iv : 0u;
    Bs1.y = (kssel == 1 && dsel == 1) ? iv : 0u;
    Bs1.z = (kssel == 1 && dsel == 2) ? iv : 0u;
    Bs1.w = (kssel == 1 && dsel == 3) ? iv : 0u;
    Bs2.x = (kssel == 2 && dsel == 0) ? iv : 0u;
    Bs2.y = (kssel == 2 && dsel == 1) ? iv : 0u;
    Bs2.z = (kssel == 2 && dsel == 2) ? iv : 0u;
    Bs2.w = (kssel == 2 && dsel == 3) ? iv : 0u;
    Bs3.x = (kssel == 3 && dsel == 0) ? iv : 0u;
    Bs3.y = (kssel == 3 && dsel == 1) ? iv : 0u;
    Bs3.z = (kssel == 3 && dsel == 2) ? iv : 0u;
    Bs3.w = (kssel == 3 && dsel == 3) ? iv : 0u;
  }

  float rs = 1.0f, llacc = 0.0f, fmA = 1.0f;
  fx4 zz4; zz4.x = 0.f; zz4.y = 0.f; zz4.z = 0.f; zz4.w = 0.f;

  // accumulator ping-pong sets (function scope; liveness alternates)
  fx4 cA0, cA1, cA2, cA3, cA4, cA5, cA6, cA7;
  fx4 cB0, cB1, cB2, cB3, cB4, cB5, cB6, cB7;

  int tk0 = xseg[0], tk1 = xseg[1];
  int tkA = xseg[2], tkB = xseg[3];
  uint2 qc0, qc1, qc2, qc3, qc4, qc5, qc6, qc7;
  uint2 qn0, qn1, qn2, qn3, qn4, qn5, qn6, qn7;
  QLD(qc0, tk0, 0) QLD(qc1, tk0, 1) QLD(qc2, tk0, 2) QLD(qc3, tk0, 3)
  QLD(qc4, tk0, 4) QLD(qc5, tk0, 5) QLD(qc6, tk0, 6) QLD(qc7, tk0, 7)
  QLD(qn0, tk1, 0) QLD(qn1, tk1, 1) QLD(qn2, tk1, 2) QLD(qn3, tk1, 3)
  QLD(qn4, tk1, 4) QLD(qn5, tk1, 5) QLD(qn6, tk1, 6) QLD(qn7, tk1, 7)

  // prologue: cA = T^T * S_0 (identity)
  MST0(cA, Bs0) MSTA(cA, Bs1, 1) MSTA(cA, Bs2, 2) MSTA(cA, Bs3, 3)

  // de-phase waves within a block (co-resident waves are usually from
  // different blocks now; this is residual, harmless)
  if (wv & 1) __builtin_amdgcn_s_sleep(8);

  for (int f4 = 0; f4 < 128; ++f4) {
    int f = f4 * 4;
    SLOT_RS(cA, cB, qc, tkA, f)
    SLOT_NR(cB, cA, qn, tkB, f + 1)
    SLOT_NR(cA, cB, qc, tkA, f + 2)
    SLOT_NR(cB, cA, qn, tkB, f + 3)
  }

  // final S (state after token 511) sits in Bs0..3 (slot 3's PKPAIR).
  // Lane (c,quad) holds P[row=16gw+c][col-pairs]: dword d of Bs[ks] is
  // col-pair index 16ks + (d<2 ? 2quad+d : 8+2quad+(d-2)).
  size_t pb = (size_t)seg * 8192 + (size_t)(16 * gw + c) * 64;
  uint2 st;
  st.x = Bs0.x; st.y = Bs0.y; *(uint2*)(Pst + pb +  0 + 2 * quad) = st;
  st.x = Bs0.z; st.y = Bs0.w; *(uint2*)(Pst + pb +  8 + 2 * quad) = st;
  st.x = Bs1.x; st.y = Bs1.y; *(uint2*)(Pst + pb + 16 + 2 * quad) = st;
  st.x = Bs1.z; st.y = Bs1.w; *(uint2*)(Pst + pb + 24 + 2 * quad) = st;
  st.x = Bs2.x; st.y = Bs2.y; *(uint2*)(Pst + pb + 32 + 2 * quad) = st;
  st.x = Bs2.z; st.y = Bs2.w; *(uint2*)(Pst + pb + 40 + 2 * quad) = st;
  st.x = Bs3.x; st.y = Bs3.y; *(uint2*)(Pst + pb + 48 + 2 * quad) = st;
  st.x = Bs3.z; st.y = Bs3.w; *(uint2*)(Pst + pb + 56 + 2 * quad) = st;
  if (quad == 0)
    LLseg[(size_t)seg * 128 + 16 * gw + c] = llacc * 0.6931471805599453f;
}

// =====================================================================
// PHASE 2: per chain, alpha0 -> fold 8 segment matrices, accumulate LL.
// =====================================================================
__global__ __launch_bounds__(64, 1) void k_comb(
    const float* __restrict__ start_w, const float* __restrict__ start_b,
    const uint* __restrict__ Pst, const float* __restrict__ LLseg,
    float* __restrict__ chainLL) {
  __shared__ uint al[64] __attribute__((aligned(16)));
  int n = blockIdx.x, l = threadIdx.x;
  float a0i = start_w[2 * l] + start_b[2 * l];
  float a1i = start_w[2 * l + 1] + start_b[2 * l + 1];
  float m = fmaxf(a0i, a1i);
  #pragma unroll
  for (int s = 1; s < 64; s <<= 1) m = fmaxf(m, __shfl_xor(m, s, 64));
  float p0 = __expf(a0i - m), p1 = __expf(a1i - m);
  float tot = p0 + p1;
  #pragma unroll
  for (int s = 1; s < 64; s <<= 1) tot += __shfl_xor(tot, s, 64);
  float LLacc = m + __logf(tot);
  float inv = 1.0f / tot;
  p0 *= inv; p1 *= inv;
  const uint4_a* u4 = (const uint4_a*)al;

  for (int s = 0; s < 8; ++s) {
    float La = LLseg[(size_t)(n * 8 + s) * 128 + 2 * l];
    float Lb = LLseg[(size_t)(n * 8 + s) * 128 + 2 * l + 1];
    float g = fmaxf(La, Lb);
    #pragma unroll
    for (int sh = 1; sh < 64; sh <<= 1) g = fmaxf(g, __shfl_xor(g, sh, 64));
    al[l] = bfpack(p0 * __expf(La - g), p1 * __expf(Lb - g));

    const uint* pb = Pst + (size_t)(n * 8 + s) * 8192;
    float o0 = 0.f, o1 = 0.f;
    #pragma unroll
    for (int i = 0; i < 16; ++i) {
      uint4 uu = u4[i];
      #pragma unroll
      for (int d = 0; d < 4; ++d) {
        uint ad = (d == 0) ? uu.x : (d == 1) ? uu.y : (d == 2) ? uu.z : uu.w;
        uint P0 = pb[(8 * i + 2 * d) * 64 + l];
        uint P1 = pb[(8 * i + 2 * d + 1) * 64 + l];
        float alo = bflo(ad), ahi = bfhi(ad);
        o0 = fmaf(alo, bflo(P0), o0); o0 = fmaf(ahi, bflo(P1), o0);
        o1 = fmaf(alo, bfhi(P0), o1); o1 = fmaf(ahi, bfhi(P1), o1);
      }
    }
    float tt = o0 + o1;
    #pragma unroll
    for (int sh = 1; sh < 64; sh <<= 1) tt += __shfl_xor(tt, sh, 64);
    LLacc += g + __logf(tt);
    float it = 1.0f / tt;
    p0 = o0 * it; p1 = o1 * it;
  }
  if (l == 0) chainLL[n] = LLacc;
}

// =====================================================================
// FALLBACK (R9): sequential scan, 4 waves per chain — used if ws too small
// =====================================================================
#define RLU(i) ((uint)__builtin_amdgcn_readlane((int)ud, rbase + (i)))
#if HAVE_BFDOT
#define DOTS \
  uint u0=RLU(0),u1=RLU(1),u2=RLU(2),u3=RLU(3),u4=RLU(4),u5=RLU(5),u6=RLU(6),u7=RLU(7), \
       u8=RLU(8),u9=RLU(9),u10=RLU(10),u11=RLU(11),u12=RLU(12),u13=RLU(13),u14=RLU(14),u15=RLU(15); \
  float A0 = dot2bf(u0, tA0.x, 0.f), A1 = dot2bf(u1, tA0.y, 0.f); \
  float A2 = dot2bf(u2, tA0.z, 0.f), A3 = dot2bf(u3, tA0.w, 0.f); \
  float B0 = dot2bf(u0, tB0.x, 0.f), B1 = dot2bf(u1, tB0.y, 0.f); \
  float B2 = dot2bf(u2, tB0.z, 0.f), B3 = dot2bf(u3, tB0.w, 0.f); \
  A0 = dot2bf(u4, tA1.x, A0); A1 = dot2bf(u5, tA1.y, A1); \
  A2 = dot2bf(u6, tA1.z, A2); A3 = dot2bf(u7, tA1.w, A3); \
  B0 = dot2bf(u4, tB1.x, B0); B1 = dot2bf(u5, tB1.y, B1); \
  B2 = dot2bf(u6, tB1.z, B2); B3 = dot2bf(u7, tB1.w, B3); \
  A0 = dot2bf(u8, tA2.x, A0); A1 = dot2bf(u9, tA2.y, A1); \
  A2 = dot2bf(u10, tA2.z, A2); A3 = dot2bf(u11, tA2.w, A3); \
  B0 = dot2bf(u8, tB2.x, B0); B1 = dot2bf(u9, tB2.y, B1); \
  B2 = dot2bf(u10, tB2.z, B2); B3 = dot2bf(u11, tB2.w, B3); \
  A0 = dot2bf(u12, tA3.x, A0); A1 = dot2bf(u13, tA3.y, A1); \
  A2 = dot2bf(u14, tA3.z, A2); A3 = dot2bf(u15, tA3.w, A3); \
  B0 = dot2bf(u12, tB3.x, B0); B1 = dot2bf(u13, tB3.y, B1); \
  B2 = dot2bf(u14, tB3.z, B2); B3 = dot2bf(u15, tB3.w, B3); \
  float Asum = (A0 + A1) + (A2 + A3), Bsum = (B0 + B1) + (B2 + B3);
#else
#define ACC2(i, AA, BB) { uint tu = RLU(i); float lo = bflo(tu), hi = bfhi(tu); \
  AA += lo * fa##i.x; AA += hi * fa##i.y; BB += lo * fb##i.x; BB += hi * fb##i.y; }
#define DOTS \
  float A0 = 0.f, A1 = 0.f, A2 = 0.f, A3 = 0.f; \
  float B0 = 0.f, B1 = 0.f, B2 = 0.f, B3 = 0.f; \
  ACC2(0, A0, B0) ACC2(1, A1, B1) ACC2(2, A2, B2) ACC2(3, A3, B3) \
  ACC2(4, A0, B0) ACC2(5, A1, B1) ACC2(6, A2, B2) ACC2(7, A3, B3) \
  ACC2(8, A0, B0) ACC2(9, A1, B1) ACC2(10, A2, B2) ACC2(11, A3, B3) \
  ACC2(12, A0, B0) ACC2(13, A1, B1) ACC2(14, A2, B2) ACC2(15, A3, B3) \
  float Asum = (A0 + A1) + (A2 + A3), Bsum = (B0 + B1) + (B2 + B3);
#endif

#define STEPF(j, p) { \
  DOTS \
  *(float2*)&partLDS[(p) * 640 + l * 10 + 2 * wv] = make_float2(Asum, Bsum); \
  asm volatile("s_waitcnt lgkmcnt(0)\ns_barrier" ::: "memory"); \
  const float2* pr = (const float2*)&partLDS[(p) * 640 + l * 10]; \
  float2 x0 = pr[0], x1 = pr[1], x2 = pr[2], x3 = pr[3]; \
  float s0 = (x0.x + x1.x) + (x2.x + x3.x); \
  float s1 = (x0.y + x1.y) + (x2.y + x3.y); \
  float nu0 = s0 * bflo(qc##j), nu1 = s1 * bfhi(qc##j); \
  qc##j = qtbl[(size_t)tk##j * 64 + l]; \
  tk##j = xrow[(tbase + (j) + 16) & 4095]; \
  if ((j) == 7) { \
    float tt = nu0 + nu1; \
    for (int s = 1; s < 64; s <<= 1) tt += __shfl_xor(tt, s, 64); \
    LLacc += __logf(tt); \
    float it = 1.0f / tt; nu0 *= it; nu1 *= it; \
  } \
  ud = bfpack(nu0, nu1); }

__global__ __launch_bounds__(256, 1) void k_chain(const int* __restrict__ x,
    const float* __restrict__ start_w, const float* __restrict__ start_b,
    const uint* __restrict__ Tcol, const uint* __restrict__ qtbl,
    float* __restrict__ chainLL) {
  __shared__ float partLDS[1280];
  int n = blockIdx.x;
  int l = threadIdx.x & 63;
  int wv = __builtin_amdgcn_readfirstlane((int)(threadIdx.x >> 6));
  int rbase = wv * 16;
  const int* xrow = x + (size_t)n * 4096;

  const uint4* ca = (const uint4*)(Tcol + (2 * l) * 64 + rbase);
  const uint4* cb = (const uint4*)(Tcol + (2 * l + 1) * 64 + rbase);
  uint4 tA0 = ca[0], tA1 = ca[1], tA2 = ca[2], tA3 = ca[3];
  uint4 tB0 = cb[0], tB1 = cb[1], tB2 = cb[2], tB3 = cb[3];
#if !HAVE_BFDOT
  float2 fa0 = make_float2(bflo(tA0.x), bfhi(tA0.x)), fa1 = make_float2(bflo(tA0.y), bfhi(tA0.y));
  float2 fa2 = make_float2(bflo(tA0.z), bfhi(tA0.z)), fa3 = make_float2(bflo(tA0.w), bfhi(tA0.w));
  float2 fa4 = make_float2(bflo(tA1.x), bfhi(tA1.x)), fa5 = make_float2(bflo(tA1.y), bfhi(tA1.y));
  float2 fa6 = make_float2(bflo(tA1.z), bfhi(tA1.z)), fa7 = make_float2(bflo(tA1.w), bfhi(tA1.w));
  float2 fa8 = make_float2(bflo(tA2.x), bfhi(tA2.x)), fa9 = make_float2(bflo(tA2.y), bfhi(tA2.y));
  float2 fa10 = make_float2(bflo(tA2.z), bfhi(tA2.z)), fa11 = make_float2(bflo(tA2.w), bfhi(tA2.w));
  float2 fa12 = make_float2(bflo(tA3.x), bfhi(tA3.x)), fa13 = make_float2(bflo(tA3.y), bfhi(tA3.y));
  float2 fa14 = make_float2(bflo(tA3.z), bfhi(tA3.z)), fa15 = make_float2(bflo(tA3.w), bfhi(tA3.w));
  float2 fb0 = make_float2(bflo(tB0.x), bfhi(tB0.x)), fb1 = make_float2(bflo(tB0.y), bfhi(tB0.y));
  float2 fb2 = make_float2(bflo(tB0.z), bfhi(tB0.z)), fb3 = make_float2(bflo(tB0.w), bfhi(tB0.w));
  float2 fb4 = make_float2(bflo(tB1.x), bfhi(tB1.x)), fb5 = make_float2(bflo(tB1.y), bfhi(tB1.y));
  float2 fb6 = make_float2(bflo(tB1.z), bfhi(tB1.z)), fb7 = make_float2(bflo(tB1.w), bfhi(tB1.w));
  float2 fb8 = make_float2(bflo(tB2.x), bfhi(tB2.x)), fb9 = make_float2(bflo(tB2.y), bfhi(tB2.y));
  float2 fb10 = make_float2(bflo(tB2.z), bfhi(tB2.z)), fb11 = make_float2(bflo(tB2.w), bfhi(tB2.w));
  float2 fb12 = make_float2(bflo(tB3.x), bfhi(tB3.x)), fb13 = make_float2(bflo(tB3.y), bfhi(tB3.y));
  float2 fb14 = make_float2(bflo(tB3.z), bfhi(tB3.z)), fb15 = make_float2(bflo(tB3.w), bfhi(tB3.w));
#endif

  float a0i = start_w[2 * l] + start_b[2 * l];
  float a1i = start_w[2 * l + 1] + start_b[2 * l + 1];
  float m = fmaxf(a0i, a1i);
  #pragma unroll
  for (int s = 1; s < 64; s <<= 1) m = fmaxf(m, __shfl_xor(m, s, 64));
  float p0 = __expf(a0i - m), p1 = __expf(a1i - m);
  float tot = p0 + p1;
  #pragma unroll
  for (int s = 1; s < 64; s <<= 1) tot += __shfl_xor(tot, s, 64);
  float LLacc = m + __logf(tot);
  float inv = 1.0f / tot;
  uint ud = bfpack(p0 * inv, p1 * inv);

  uint qc0 = qtbl[(size_t)xrow[0] * 64 + l], qc1 = qtbl[(size_t)xrow[1] * 64 + l];
  uint qc2 = qtbl[(size_t)xrow[2] * 64 + l], qc3 = qtbl[(size_t)xrow[3] * 64 + l];
  uint qc4 = qtbl[(size_t)xrow[4] * 64 + l], qc5 = qtbl[(size_t)xrow[5] * 64 + l];
  uint qc6 = qtbl[(size_t)xrow[6] * 64 + l], qc7 = qtbl[(size_t)xrow[7] * 64 + l];
  int tk0 = xrow[8],  tk1 = xrow[9],  tk2 = xrow[10], tk3 = xrow[11];
  int tk4 = xrow[12], tk5 = xrow[13], tk6 = xrow[14], tk7 = xrow[15];

  for (int t8 = 0; t8 < 512; ++t8) {
    int tbase = t8 * 8;
    STEPF(0, 0) STEPF(1, 1) STEPF(2, 0) STEPF(3, 1)
    STEPF(4, 0) STEPF(5, 1) STEPF(6, 0) STEPF(7, 1)
  }
  if (l == 0 && wv == 0) chainLL[n] = LLacc;
}

// ---------- K4a: sum of Emax over all tokens ----------
__global__ __launch_bounds__(256) void k_emaxsum(const int* __restrict__ x,
    const float* __restrict__ Emax, float* __restrict__ sumE, int NT) {
  int idx = blockIdx.x * 256 + threadIdx.x;
  float s = 0.f;
  for (; idx < NT; idx += 128 * 256) s += Emax[x[idx]];
  #pragma unroll
  for (int mk = 1; mk < 64; mk <<= 1) s += __shfl_xor(s, mk, 64);
  if ((threadIdx.x & 63) == 0) atomicAdd(sumE, s);
}

// ---------- K4b: final scalar ----------
__global__ void k_final(const float* __restrict__ chainLL, const float* __restrict__ sumE,
                        float* __restrict__ out, int N) {
  int l = threadIdx.x;
  float v = (l < N) ? chainLL[l] : 0.f;
  #pragma unroll
  for (int mk = 1; mk < 64; mk <<= 1) v += __shfl_xor(v, mk, 64);
  if (l == 0) out[0] = -(v + sumE[0]) / (float)N;
}

extern "C" void kernel_launch(void* const* d_in, const int* in_sizes, int n_in,
                              void* d_out, int out_size, void* d_ws, size_t ws_size,
                              hipStream_t stream) {
  if (n_in < 6) return;
  const int*   x       = (const int*)d_in[0];
  const float* start_w = (const float*)d_in[1];
  const float* start_b = (const float*)d_in[2];
  const float* trans_w = (const float*)d_in[3];
  const float* emb_w   = (const float*)d_in[4];
  const float* vocab_w = (const float*)d_in[5];
  int NT = in_sizes[0];
  int N  = NT / 4096;
  int V  = in_sizes[5] / 128;

  char* ws = (char*)d_ws;
  float* S_glob  = (float*)(ws + 0);        // 128 f
  float* sumE    = (float*)(ws + 512);      // 1 f
  float* chainLL = (float*)(ws + 768);      // N f
  uint*  Tcol    = (uint*)(ws + 1024);      // 32 KB
  float* Emax    = (float*)(ws + 36864);    // V floats (ends 236864)
  uint*  qtbl    = (uint*)(ws + 262144);    // V*64 dwords = V*256 B
  size_t pst_off = 262144 + (size_t)V * 256;
  uint*  Pst     = (uint*)(ws + pst_off);   // N*8*8192 dwords
  size_t llseg_off = pst_off + (size_t)N * 8 * 8192 * 4;
  float* LLseg   = (float*)(ws + llseg_off);  // N*8*128 floats
  size_t need    = llseg_off + (size_t)N * 8 * 128 * 4 + 64;

  hipMemsetAsync(d_ws, 0, 1024, stream);
  k_tran<<<dim3(1), dim3(128), 0, stream>>>(trans_w, Tcol);
  k_logits<<<dim3((V + 63) / 64), dim3(256), 0, stream>>>(emb_w, vocab_w, qtbl, S_glob, V);
  k_qtab<<<dim3((V + 3) / 4), dim3(256), 0, stream>>>(qtbl, S_glob, Emax, V);
  if (ws_size >= need) {
    k_seg<<<dim3(N * 16), dim3(256), 0, stream>>>(x, Tcol, qtbl, Pst, LLseg);
    k_comb<<<dim3(N), dim3(64), 0, stream>>>(start_w, start_b, Pst, LLseg, chainLL);
  } else {
    k_chain<<<dim3(N), dim3(256), 0, stream>>>(x, start_w, start_b, Tcol, qtbl, chainLL);
  }
  k_emaxsum<<<dim3(128), dim3(256), 0, stream>>>(x, Emax, sumE, NT);
  k_final<<<dim3(1), dim3(64), 0, stream>>>(chainLL, sumE, (float*)d_out, N);
}

// Round 11
// 698.150 us; speedup vs baseline: 1.0657x; 1.0657x over previous
//
#include <hip/hip_runtime.h>

typedef unsigned int uint;
typedef unsigned short ushort;
typedef uint4 uint4_a __attribute__((may_alias));
typedef uint ui4v __attribute__((ext_vector_type(4)));
typedef float fx4 __attribute__((ext_vector_type(4)));
typedef short s8v __attribute__((ext_vector_type(8)));

// ---------- bf16 helpers ----------
__device__ __forceinline__ uint bfpack(float a, float b) {
  uint ua = __float_as_uint(a), ub = __float_as_uint(b);
  ua += 0x7fffu + ((ua >> 16) & 1u);   // RNE
  ub += 0x7fffu + ((ub >> 16) & 1u);
  return (ua >> 16) | (ub & 0xffff0000u);
}
__device__ __forceinline__ float bflo(uint d) { return __uint_as_float(d << 16); }
__device__ __forceinline__ float bfhi(uint d) { return __uint_as_float(d & 0xffff0000u); }
__device__ __forceinline__ ushort bfr(float s) {          // round-half-up f32->bf16
  return (ushort)((__float_as_uint(s) + 0x8000u) >> 16);
}

#if __has_builtin(__builtin_amdgcn_fdot2_f32_bf16)
#define HAVE_BFDOT 1
typedef __bf16 v2bf __attribute__((ext_vector_type(2)));
__device__ __forceinline__ float dot2bf(uint a, uint b, float c) {
  return __builtin_amdgcn_fdot2_f32_bf16(__builtin_bit_cast(v2bf, a),
                                         __builtin_bit_cast(v2bf, b), c, false);
}
#else
#define HAVE_BFDOT 0
#endif

// ---------- K1: transition table, column-pair layout (64 blocks) ----------
// Tcol[c*64 + j] = bf16x2( exp(tran[2j][c]), exp(tran[2j+1][c]) )
// Block b handles columns {2b, 2b+1}; rowLSE computed redundantly per block.
__global__ __launch_bounds__(128) void k_tran(const float* __restrict__ w,
                                              uint* __restrict__ Tcol) {
  __shared__ float rowLSE[128];
  int tid = threadIdx.x;                       // 128 threads
  const float4* w4 = (const float4*)(w + tid * 128);
  float se = 0.f;
  #pragma unroll 8
  for (int i = 0; i < 32; ++i) {
    float4 v = w4[i];
    se += __expf(v.x) + __expf(v.y) + __expf(v.z) + __expf(v.w);
  }
  rowLSE[tid] = __logf(se);
  __syncthreads();
  int j = tid & 63;
  int c = 2 * blockIdx.x + (tid >> 6);
  float a = __expf(w[(2 * j) * 128 + c]     - rowLSE[2 * j]);
  float b = __expf(w[(2 * j + 1) * 128 + c] - rowLSE[2 * j + 1]);
  Tcol[c * 64 + j] = bfpack(a, b);
}

// ---------- K2a: logits (bf16, pair layout) + per-k sum of exp(logit) ----------
__global__ __launch_bounds__(256) void k_logits(const float* __restrict__ emb,
    const float* __restrict__ vocab, uint* __restrict__ qtbl,
    float* __restrict__ S_glob, int V) {
  __shared__ float S_part[128];
  int tid = threadIdx.x;
  int kt = tid & 15, vt = tid >> 4;
  int k0 = kt * 8;
  int vbase = blockIdx.x * 64 + vt * 4;
  if (tid < 128) S_part[tid] = 0.f;
  __syncthreads();

  float acc[4][8];
  #pragma unroll
  for (int i = 0; i < 4; ++i)
    #pragma unroll
    for (int r = 0; r < 8; ++r) acc[i][r] = 0.f;

  int vidx[4];
  #pragma unroll
  for (int i = 0; i < 4; ++i) { int vv = vbase + i; vidx[i] = (vv < V) ? vv : (V - 1); }

  const float4* emb4 = (const float4*)emb;
  const float4* voc4 = (const float4*)vocab;
  for (int jb = 0; jb < 32; ++jb) {
    float4 e4[8];
    #pragma unroll
    for (int r = 0; r < 8; ++r) e4[r] = emb4[(k0 + r) * 32 + jb];
    #pragma unroll
    for (int i = 0; i < 4; ++i) {
      float4 va = voc4[(size_t)vidx[i] * 32 + jb];
      #pragma unroll
      for (int r = 0; r < 8; ++r)
        acc[i][r] += va.x * e4[r].x + va.y * e4[r].y + va.z * e4[r].z + va.w * e4[r].w;
    }
  }

  float sume[8];
  #pragma unroll
  for (int r = 0; r < 8; ++r) sume[r] = 0.f;
  #pragma unroll
  for (int i = 0; i < 4; ++i) {
    int vv = vbase + i;
    if (vv < V) {
      #pragma unroll
      for (int r = 0; r < 8; ++r) sume[r] += __expf(acc[i][r]);
      uint4 st;
      st.x = bfpack(acc[i][0], acc[i][1]);
      st.y = bfpack(acc[i][2], acc[i][3]);
      st.z = bfpack(acc[i][4], acc[i][5]);
      st.w = bfpack(acc[i][6], acc[i][7]);
      *((uint4*)(qtbl + (size_t)vv * 64) + kt) = st;
    }
  }
  #pragma unroll
  for (int r = 0; r < 8; ++r) atomicAdd(&S_part[k0 + r], sume[r]);
  __syncthreads();
  if (tid < 128) atomicAdd(&S_glob[tid], S_part[tid]);
}

// ---------- K2c: in-place q[v][k] = exp(emis - Emax_v) (bf16), Emax table ----------
__global__ __launch_bounds__(256) void k_qtab(uint* __restrict__ qtbl,
    const float* __restrict__ S_glob, float* __restrict__ Emax, int V) {
  int tid = threadIdx.x;
  int l = tid & 63;
  int v = blockIdx.x * 4 + (tid >> 6);
  if (v >= V) return;
  float2 S2 = ((const float2*)S_glob)[l];
  float z0 = __logf(S2.x), z1 = __logf(S2.y);
  size_t off = (size_t)v * 64 + l;
  uint d = qtbl[off];
  float e0 = bflo(d) - z0, e1 = bfhi(d) - z1;
  float m = fmaxf(e0, e1);
  #pragma unroll
  for (int s = 1; s < 64; s <<= 1) m = fmaxf(m, __shfl_xor(m, s, 64));
  float q0 = __expf(e0 - m), q1 = __expf(e1 - m);
  qtbl[off] = bfpack(q0, q1);
  if (l == 0) Emax[v] = m;
}

// =====================================================================
// PHASE 1 (S-form, register-resident, stage-pipelined): per (chain,
// segment) compute P_seg = prod_t (T D_t) via S <- D_t (T^T S).
// R9-exact structure (best measured: 520 us).  8 waves/block, wave wv
// owns S columns [16wv,16wv+16).  T^T frags static in AGPRs; relabeled
// k-order so each lane's MFMA C-output IS its own next-fold B-fragment
// after scale+cvt_pk (zero LDS/cross-lane).  Rescale every 4th fold
// (guarded).  PLATEAU NOTE: MfmaUtil ~49% at 2 waves/SIMD; stage-pipe
// (R9) and wave-decorrelation (R10) both null -> per-wave dependent-
// issue bound; 2 waves/SIMD is reg-file-capped (128 VGPR + 128 AGPR).
// =====================================================================
#define REPB(M) M(0,0) M(0,1) M(0,2) M(0,3) M(1,0) M(1,1) M(1,2) M(1,3) \
                M(2,0) M(2,1) M(2,2) M(2,3) M(3,0) M(3,1) M(3,2) M(3,3) \
                M(4,0) M(4,1) M(4,2) M(4,3) M(5,0) M(5,1) M(5,2) M(5,3) \
                M(6,0) M(6,1) M(6,2) M(6,3) M(7,0) M(7,1) M(7,2) M(7,3)

#define MFMA(a, b, c) __builtin_amdgcn_mfma_f32_16x16x32_bf16( \
    __builtin_bit_cast(s8v, a), __builtin_bit_cast(s8v, b), c, 0, 0, 0)

#define MST0(OUT, BN) \
  OUT##0 = MFMA(tb0_0, BN, zz4); OUT##1 = MFMA(tb1_0, BN, zz4); \
  OUT##2 = MFMA(tb2_0, BN, zz4); OUT##3 = MFMA(tb3_0, BN, zz4); \
  OUT##4 = MFMA(tb4_0, BN, zz4); OUT##5 = MFMA(tb5_0, BN, zz4); \
  OUT##6 = MFMA(tb6_0, BN, zz4); OUT##7 = MFMA(tb7_0, BN, zz4);
#define MSTA(OUT, BN, ks) \
  OUT##0 = MFMA(tb0_##ks, BN, OUT##0); OUT##1 = MFMA(tb1_##ks, BN, OUT##1); \
  OUT##2 = MFMA(tb2_##ks, BN, OUT##2); OUT##3 = MFMA(tb3_##ks, BN, OUT##3); \
  OUT##4 = MFMA(tb4_##ks, BN, OUT##4); OUT##5 = MFMA(tb5_##ks, BN, OUT##5); \
  OUT##6 = MFMA(tb6_##ks, BN, OUT##6); OUT##7 = MFMA(tb7_##ks, BN, OUT##7);

#define PKPAIR(CCA, CCB, QA, QB, DOUT) { \
  float f0 = bflo(QA.x) * rs, f1 = bfhi(QA.x) * rs; \
  float f2 = bflo(QA.y) * rs, f3 = bfhi(QA.y) * rs; \
  float s0 = CCA.x * f0, s1 = CCA.y * f1, s2 = CCA.z * f2, s3 = CCA.w * f3; \
  fm = fmaxf(fm, fmaxf(fmaxf(s0, s1), fmaxf(s2, s3))); \
  uint p0, p1, p2, p3; \
  asm("v_cvt_pk_bf16_f32 %0, %1, %2" : "=v"(p0) : "v"(s0), "v"(s1)); \
  asm("v_cvt_pk_bf16_f32 %0, %1, %2" : "=v"(p1) : "v"(s2), "v"(s3)); \
  float g0 = bflo(QB.x) * rs, g1 = bfhi(QB.x) * rs; \
  float g2 = bflo(QB.y) * rs, g3 = bfhi(QB.y) * rs; \
  float t0 = CCB.x * g0, t1 = CCB.y * g1, t2 = CCB.z * g2, t3 = CCB.w * g3; \
  fm = fmaxf(fm, fmaxf(fmaxf(t0, t1), fmaxf(t2, t3))); \
  asm("v_cvt_pk_bf16_f32 %0, %1, %2" : "=v"(p2) : "v"(t0), "v"(t1)); \
  asm("v_cvt_pk_bf16_f32 %0, %1, %2" : "=v"(p3) : "v"(t2), "v"(t3)); \
  DOUT.x = p0; DOUT.y = p1; DOUT.z = p2; DOUT.w = p3; }

#define PKPAIR_NR(CCA, CCB, QA, QB, DOUT) { \
  float s0 = CCA.x * bflo(QA.x), s1 = CCA.y * bfhi(QA.x); \
  float s2 = CCA.z * bflo(QA.y), s3 = CCA.w * bfhi(QA.y); \
  uint p0, p1, p2, p3; \
  asm("v_cvt_pk_bf16_f32 %0, %1, %2" : "=v"(p0) : "v"(s0), "v"(s1)); \
  asm("v_cvt_pk_bf16_f32 %0, %1, %2" : "=v"(p1) : "v"(s2), "v"(s3)); \
  float t0 = CCB.x * bflo(QB.x), t1 = CCB.y * bfhi(QB.x); \
  float t2 = CCB.z * bflo(QB.y), t3 = CCB.w * bfhi(QB.y); \
  asm("v_cvt_pk_bf16_f32 %0, %1, %2" : "=v"(p2) : "v"(t0), "v"(t1)); \
  asm("v_cvt_pk_bf16_f32 %0, %1, %2" : "=v"(p3) : "v"(t2), "v"(t3)); \
  DOUT.x = p0; DOUT.y = p1; DOUT.z = p2; DOUT.w = p3; }

#define QLD(dst, tk, i) dst = *(const uint2*)(qtbl + ((size_t)(tk) << 6) + 8 * (i) + 2 * quad);

#define QRELOAD(Q, TKREG, FBASE) \
  QLD(Q##0, TKREG, 0) QLD(Q##1, TKREG, 1) QLD(Q##2, TKREG, 2) QLD(Q##3, TKREG, 3) \
  QLD(Q##4, TKREG, 4) QLD(Q##5, TKREG, 5) QLD(Q##6, TKREG, 6) QLD(Q##7, TKREG, 7) \
  { int fi_ = (FBASE) + 4; if (fi_ > 511) fi_ = 511; TKREG = xseg[fi_]; }

#define SLOT_RS(CIN, COUT, Q, TKREG, FBASE) { \
  rs = 1.0f / fmA;  llacc += __log2f(fmA); \
  float fm = 0.f; \
  PKPAIR(CIN##0, CIN##1, Q##0, Q##1, Bs0) \
  MST0(COUT, Bs0) \
  PKPAIR(CIN##2, CIN##3, Q##2, Q##3, Bs1) \
  MSTA(COUT, Bs1, 1) \
  PKPAIR(CIN##4, CIN##5, Q##4, Q##5, Bs2) \
  MSTA(COUT, Bs2, 2) \
  PKPAIR(CIN##6, CIN##7, Q##6, Q##7, Bs3) \
  MSTA(COUT, Bs3, 3) \
  QRELOAD(Q, TKREG, FBASE) \
  fm = fmaxf(fm, __shfl_xor(fm, 16, 64)); \
  fm = fmaxf(fm, __shfl_xor(fm, 32, 64)); \
  fmA = fmaxf(fm, 1e-33f); \
}

#define SLOT_NR(CIN, COUT, Q, TKREG, FBASE) { \
  PKPAIR_NR(CIN##0, CIN##1, Q##0, Q##1, Bs0) \
  MST0(COUT, Bs0) \
  PKPAIR_NR(CIN##2, CIN##3, Q##2, Q##3, Bs1) \
  MSTA(COUT, Bs1, 1) \
  PKPAIR_NR(CIN##4, CIN##5, Q##4, Q##5, Bs2) \
  MSTA(COUT, Bs2, 2) \
  PKPAIR_NR(CIN##6, CIN##7, Q##6, Q##7, Bs3) \
  MSTA(COUT, Bs3, 3) \
  QRELOAD(Q, TKREG, FBASE) \
}

__global__ __attribute__((amdgpu_flat_work_group_size(512, 512), amdgpu_waves_per_eu(2)))
void k_seg(const int* __restrict__ x, const uint* __restrict__ Tcol,
           const uint* __restrict__ qtbl, uint* __restrict__ Pst,
           float* __restrict__ LLseg) {
  int tid = threadIdx.x;
  int wv = tid >> 6, l = tid & 63, c = l & 15, quad = l >> 4;
  int blk = blockIdx.x;
  const int* xseg = x + (size_t)(blk >> 3) * 4096 + (size_t)(blk & 7) * 512;

  // A-frags (T^T, relabeled k-order) -> AGPRs.
  #define DECLB(nt, ks) ui4v tb##nt##_##ks;
  REPB(DECLB)
  {
    #define LOADB(nt, ks) { \
      const uint2* t2_ = (const uint2*)(Tcol + (size_t)(16 * (nt) + c) * 64 + 16 * (ks) + 2 * quad); \
      uint2 lo_ = t2_[0], hi_ = t2_[4]; \
      tb##nt##_##ks.x = lo_.x; tb##nt##_##ks.y = lo_.y; \
      tb##nt##_##ks.z = hi_.x; tb##nt##_##ks.w = hi_.y; }
    REPB(LOADB)
    #define PINB(nt, ks) asm volatile("" : "+a"(tb##nt##_##ks));
    REPB(PINB)
  }

  // B-frag staging regs; identity init for fold 0.
  ui4v Bs0, Bs1, Bs2, Bs3;
  {
    uint iv = (quad == (c >> 2)) ? (0x3F80u << (16 * (c & 1))) : 0u;
    int dsel = ((c >> 1) & 1) + 2 * (wv & 1);
    int kssel = wv >> 1;
    Bs0.x = (kssel == 0 && dsel == 0) ? iv : 0u;
    Bs0.y = (kssel == 0 && dsel == 1) ? iv : 0u;
    Bs0.z = (kssel == 0 && dsel == 2) ? iv : 0u;
    Bs0.w = (kssel == 0 && dsel == 3) ? iv : 0u;
    Bs1.x = (kssel == 1 && dsel == 0) ? iv : 0u;
    Bs1.y = (kssel == 1 && dsel == 1) ? iv : 0u;
    Bs1.z = (kssel == 1 && dsel == 2) ? iv : 0u;
    Bs1.w = (kssel == 1 && dsel == 3) ? iv : 0u;
    Bs2.x = (kssel == 2 && dsel == 0) ? iv : 0u;
    Bs2.y = (kssel == 2 && dsel == 1) ? iv : 0u;
    Bs2.z = (kssel == 2 && dsel == 2) ? iv : 0u;
    Bs2.w = (kssel == 2 && dsel == 3) ? iv : 0u;
    Bs3.x = (kssel == 3 && dsel == 0) ? iv : 0u;
    Bs3.y = (kssel == 3 && dsel == 1) ? iv : 0u;
    Bs3.z = (kssel == 3 && dsel == 2) ? iv : 0u;
    Bs3.w = (kssel == 3 && dsel == 3) ? iv : 0u;
  }

  float rs = 1.0f, llacc = 0.0f, fmA = 1.0f;
  fx4 zz4; zz4.x = 0.f; zz4.y = 0.f; zz4.z = 0.f; zz4.w = 0.f;

  fx4 cA0, cA1, cA2, cA3, cA4, cA5, cA6, cA7;
  fx4 cB0, cB1, cB2, cB3, cB4, cB5, cB6, cB7;

  int tk0 = xseg[0], tk1 = xseg[1];
  int tkA = xseg[2], tkB = xseg[3];
  uint2 qc0, qc1, qc2, qc3, qc4, qc5, qc6, qc7;
  uint2 qn0, qn1, qn2, qn3, qn4, qn5, qn6, qn7;
  QLD(qc0, tk0, 0) QLD(qc1, tk0, 1) QLD(qc2, tk0, 2) QLD(qc3, tk0, 3)
  QLD(qc4, tk0, 4) QLD(qc5, tk0, 5) QLD(qc6, tk0, 6) QLD(qc7, tk0, 7)
  QLD(qn0, tk1, 0) QLD(qn1, tk1, 1) QLD(qn2, tk1, 2) QLD(qn3, tk1, 3)
  QLD(qn4, tk1, 4) QLD(qn5, tk1, 5) QLD(qn6, tk1, 6) QLD(qn7, tk1, 7)

  // prologue: cA = T^T * S_0 (identity)
  MST0(cA, Bs0) MSTA(cA, Bs1, 1) MSTA(cA, Bs2, 2) MSTA(cA, Bs3, 3)

  // de-phase the 2 waves/SIMD
  if (wv & 1) __builtin_amdgcn_s_sleep(8);

  for (int f4 = 0; f4 < 128; ++f4) {
    int f = f4 * 4;
    SLOT_RS(cA, cB, qc, tkA, f)
    SLOT_NR(cB, cA, qn, tkB, f + 1)
    SLOT_NR(cA, cB, qc, tkA, f + 2)
    SLOT_NR(cB, cA, qn, tkB, f + 3)
  }

  // final S (state after token 511) sits in Bs0..3 (slot 3's PKPAIR).
  size_t pb = (size_t)blk * 8192 + (size_t)(16 * wv + c) * 64;
  uint2 st;
  st.x = Bs0.x; st.y = Bs0.y; *(uint2*)(Pst + pb +  0 + 2 * quad) = st;
  st.x = Bs0.z; st.y = Bs0.w; *(uint2*)(Pst + pb +  8 + 2 * quad) = st;
  st.x = Bs1.x; st.y = Bs1.y; *(uint2*)(Pst + pb + 16 + 2 * quad) = st;
  st.x = Bs1.z; st.y = Bs1.w; *(uint2*)(Pst + pb + 24 + 2 * quad) = st;
  st.x = Bs2.x; st.y = Bs2.y; *(uint2*)(Pst + pb + 32 + 2 * quad) = st;
  st.x = Bs2.z; st.y = Bs2.w; *(uint2*)(Pst + pb + 40 + 2 * quad) = st;
  st.x = Bs3.x; st.y = Bs3.y; *(uint2*)(Pst + pb + 48 + 2 * quad) = st;
  st.x = Bs3.z; st.y = Bs3.w; *(uint2*)(Pst + pb + 56 + 2 * quad) = st;
  if (quad == 0)
    LLseg[(size_t)blk * 128 + 16 * wv + c] = llacc * 0.6931471805599453f;
}

// =====================================================================
// PHASE 2 (4-wave): per chain, alpha0 -> fold 8 segment matrices.
// Row-dim of each 128x128 matvec split across 4 waves (32 rows each),
// partials reduced in LDS; per-lane load chain 128 -> 32.  Wave 0 owns
// the alpha state / LL bookkeeping.
// =====================================================================
__global__ __launch_bounds__(256, 1) void k_comb(
    const float* __restrict__ start_w, const float* __restrict__ start_b,
    const uint* __restrict__ Pst, const float* __restrict__ LLseg,
    float* __restrict__ chainLL) {
  __shared__ uint al[64] __attribute__((aligned(16)));
  __shared__ float2 part[4][64];
  int n = blockIdx.x, tid = threadIdx.x;
  int wv = tid >> 6, l = tid & 63;
  float p0 = 0.f, p1 = 0.f, LLacc = 0.f;
  if (wv == 0) {
    float a0i = start_w[2 * l] + start_b[2 * l];
    float a1i = start_w[2 * l + 1] + start_b[2 * l + 1];
    float m = fmaxf(a0i, a1i);
    #pragma unroll
    for (int s = 1; s < 64; s <<= 1) m = fmaxf(m, __shfl_xor(m, s, 64));
    p0 = __expf(a0i - m); p1 = __expf(a1i - m);
    float tot = p0 + p1;
    #pragma unroll
    for (int s = 1; s < 64; s <<= 1) tot += __shfl_xor(tot, s, 64);
    LLacc = m + __logf(tot);
    float inv = 1.0f / tot;
    p0 *= inv; p1 *= inv;
  }
  const uint4_a* u4 = (const uint4_a*)al;

  for (int s = 0; s < 8; ++s) {
    float g = 0.f;
    if (wv == 0) {
      float La = LLseg[(size_t)(n * 8 + s) * 128 + 2 * l];
      float Lb = LLseg[(size_t)(n * 8 + s) * 128 + 2 * l + 1];
      g = fmaxf(La, Lb);
      #pragma unroll
      for (int sh = 1; sh < 64; sh <<= 1) g = fmaxf(g, __shfl_xor(g, sh, 64));
      al[l] = bfpack(p0 * __expf(La - g), p1 * __expf(Lb - g));
    }
    __syncthreads();

    const uint* pb = Pst + (size_t)(n * 8 + s) * 8192;
    float o0 = 0.f, o1 = 0.f;
    #pragma unroll
    for (int ii = 0; ii < 4; ++ii) {
      int i = 4 * wv + ii;
      uint4 uu = u4[i];
      #pragma unroll
      for (int d = 0; d < 4; ++d) {
        uint ad = (d == 0) ? uu.x : (d == 1) ? uu.y : (d == 2) ? uu.z : uu.w;
        uint P0 = pb[(8 * i + 2 * d) * 64 + l];
        uint P1 = pb[(8 * i + 2 * d + 1) * 64 + l];
        float alo = bflo(ad), ahi = bfhi(ad);
        o0 = fmaf(alo, bflo(P0), o0); o0 = fmaf(ahi, bflo(P1), o0);
        o1 = fmaf(alo, bfhi(P0), o1); o1 = fmaf(ahi, bfhi(P1), o1);
      }
    }
    part[wv][l] = make_float2(o0, o1);
    __syncthreads();

    if (wv == 0) {
      float2 x0 = part[0][l], x1 = part[1][l], x2 = part[2][l], x3 = part[3][l];
      float s0 = (x0.x + x1.x) + (x2.x + x3.x);
      float s1 = (x0.y + x1.y) + (x2.y + x3.y);
      float tt = s0 + s1;
      #pragma unroll
      for (int sh = 1; sh < 64; sh <<= 1) tt += __shfl_xor(tt, sh, 64);
      LLacc += g + __logf(tt);
      float it = 1.0f / tt;
      p0 = s0 * it; p1 = s1 * it;
    }
  }
  if (tid == 0) chainLL[n] = LLacc;
}

// =====================================================================
// FALLBACK: sequential scan, 4 waves per chain — used if ws too small
// =====================================================================
#define RLU(i) ((uint)__builtin_amdgcn_readlane((int)ud, rbase + (i)))
#if HAVE_BFDOT
#define DOTS \
  uint u0=RLU(0),u1=RLU(1),u2=RLU(2),u3=RLU(3),u4=RLU(4),u5=RLU(5),u6=RLU(6),u7=RLU(7), \
       u8=RLU(8),u9=RLU(9),u10=RLU(10),u11=RLU(11),u12=RLU(12),u13=RLU(13),u14=RLU(14),u15=RLU(15); \
  float A0 = dot2bf(u0, tA0.x, 0.f), A1 = dot2bf(u1, tA0.y, 0.f); \
  float A2 = dot2bf(u2, tA0.z, 0.f), A3 = dot2bf(u3, tA0.w, 0.f); \
  float B0 = dot2bf(u0, tB0.x, 0.f), B1 = dot2bf(u1, tB0.y, 0.f); \
  float B2 = dot2bf(u2, tB0.z, 0.f), B3 = dot2bf(u3, tB0.w, 0.f); \
  A0 = dot2bf(u4, tA1.x, A0); A1 = dot2bf(u5, tA1.y, A1); \
  A2 = dot2bf(u6, tA1.z, A2); A3 = dot2bf(u7, tA1.w, A3); \
  B0 = dot2bf(u4, tB1.x, B0); B1 = dot2bf(u5, tB1.y, B1); \
  B2 = dot2bf(u6, tB1.z, B2); B3 = dot2bf(u7, tB1.w, B3); \
  A0 = dot2bf(u8, tA2.x, A0); A1 = dot2bf(u9, tA2.y, A1); \
  A2 = dot2bf(u10, tA2.z, A2); A3 = dot2bf(u11, tA2.w, A3); \
  B0 = dot2bf(u8, tB2.x, B0); B1 = dot2bf(u9, tB2.y, B1); \
  B2 = dot2bf(u10, tB2.z, B2); B3 = dot2bf(u11, tB2.w, B3); \
  A0 = dot2bf(u12, tA3.x, A0); A1 = dot2bf(u13, tA3.y, A1); \
  A2 = dot2bf(u14, tA3.z, A2); A3 = dot2bf(u15, tA3.w, A3); \
  B0 = dot2bf(u12, tB3.x, B0); B1 = dot2bf(u13, tB3.y, B1); \
  B2 = dot2bf(u14, tB3.z, B2); B3 = dot2bf(u15, tB3.w, B3); \
  float Asum = (A0 + A1) + (A2 + A3), Bsum = (B0 + B1) + (B2 + B3);
#else
#define ACC2(i, AA, BB) { uint tu = RLU(i); float lo = bflo(tu), hi = bfhi(tu); \
  AA += lo * fa##i.x; AA += hi * fa##i.y; BB += lo * fb##i.x; BB += hi * fb##i.y; }
#define DOTS \
  float A0 = 0.f, A1 = 0.f, A2 = 0.f, A3 = 0.f; \
  float B0 = 0.f, B1 = 0.f, B2 = 0.f, B3 = 0.f; \
  ACC2(0, A0, B0) ACC2(1, A1, B1) ACC2(2, A2, B2) ACC2(3, A3, B3) \
  ACC2(4, A0, B0) ACC2(5, A1, B1) ACC2(6, A2, B2) ACC2(7, A3, B3) \
  ACC2(8, A0, B0) ACC2(9, A1, B1) ACC2(10, A2, B2) ACC2(11, A3, B3) \
  ACC2(12, A0, B0) ACC2(13, A1, B1) ACC2(14, A2, B2) ACC2(15, A3, B3) \
  float Asum = (A0 + A1) + (A2 + A3), Bsum = (B0 + B1) + (B2 + B3);
#endif

#define STEPF(j, p) { \
  DOTS \
  *(float2*)&partLDS[(p) * 640 + l * 10 + 2 * wv] = make_float2(Asum, Bsum); \
  asm volatile("s_waitcnt lgkmcnt(0)\ns_barrier" ::: "memory"); \
  const float2* pr = (const float2*)&partLDS[(p) * 640 + l * 10]; \
  float2 x0 = pr[0], x1 = pr[1], x2 = pr[2], x3 = pr[3]; \
  float s0 = (x0.x + x1.x) + (x2.x + x3.x); \
  float s1 = (x0.y + x1.y) + (x2.y + x3.y); \
  float nu0 = s0 * bflo(qc##j), nu1 = s1 * bfhi(qc##j); \
  qc##j = qtbl[(size_t)tk##j * 64 + l]; \
  tk##j = xrow[(tbase + (j) + 16) & 4095]; \
  if ((j) == 7) { \
    float tt = nu0 + nu1; \
    for (int s = 1; s < 64; s <<= 1) tt += __shfl_xor(tt, s, 64); \
    LLacc += __logf(tt); \
    float it = 1.0f / tt; nu0 *= it; nu1 *= it; \
  } \
  ud = bfpack(nu0, nu1); }

__global__ __launch_bounds__(256, 1) void k_chain(const int* __restrict__ x,
    const float* __restrict__ start_w, const float* __restrict__ start_b,
    const uint* __restrict__ Tcol, const uint* __restrict__ qtbl,
    float* __restrict__ chainLL) {
  __shared__ float partLDS[1280];
  int n = blockIdx.x;
  int l = threadIdx.x & 63;
  int wv = __builtin_amdgcn_readfirstlane((int)(threadIdx.x >> 6));
  int rbase = wv * 16;
  const int* xrow = x + (size_t)n * 4096;

  const uint4* ca = (const uint4*)(Tcol + (2 * l) * 64 + rbase);
  const uint4* cb = (const uint4*)(Tcol + (2 * l + 1) * 64 + rbase);
  uint4 tA0 = ca[0], tA1 = ca[1], tA2 = ca[2], tA3 = ca[3];
  uint4 tB0 = cb[0], tB1 = cb[1], tB2 = cb[2], tB3 = cb[3];
#if !HAVE_BFDOT
  float2 fa0 = make_float2(bflo(tA0.x), bfhi(tA0.x)), fa1 = make_float2(bflo(tA0.y), bfhi(tA0.y));
  float2 fa2 = make_float2(bflo(tA0.z), bfhi(tA0.z)), fa3 = make_float2(bflo(tA0.w), bfhi(tA0.w));
  float2 fa4 = make_float2(bflo(tA1.x), bfhi(tA1.x)), fa5 = make_float2(bflo(tA1.y), bfhi(tA1.y));
  float2 fa6 = make_float2(bflo(tA1.z), bfhi(tA1.z)), fa7 = make_float2(bflo(tA1.w), bfhi(tA1.w));
  float2 fa8 = make_float2(bflo(tA2.x), bfhi(tA2.x)), fa9 = make_float2(bflo(tA2.y), bfhi(tA2.y));
  float2 fa10 = make_float2(bflo(tA2.z), bfhi(tA2.z)), fa11 = make_float2(bflo(tA2.w), bfhi(tA2.w));
  float2 fa12 = make_float2(bflo(tA3.x), bfhi(tA3.x)), fa13 = make_float2(bflo(tA3.y), bfhi(tA3.y));
  float2 fa14 = make_float2(bflo(tA3.z), bfhi(tA3.z)), fa15 = make_float2(bflo(tA3.w), bfhi(tA3.w));
  float2 fb0 = make_float2(bflo(tB0.x), bfhi(tB0.x)), fb1 = make_float2(bflo(tB0.y), bfhi(tB0.y));
  float2 fb2 = make_float2(bflo(tB0.z), bfhi(tB0.z)), fb3 = make_float2(bflo(tB0.w), bfhi(tB0.w));
  float2 fb4 = make_float2(bflo(tB1.x), bfhi(tB1.x)), fb5 = make_float2(bflo(tB1.y), bfhi(tB1.y));
  float2 fb6 = make_float2(bflo(tB1.z), bfhi(tB1.z)), fb7 = make_float2(bflo(tB1.w), bfhi(tB1.w));
  float2 fb8 = make_float2(bflo(tB2.x), bfhi(tB2.x)), fb9 = make_float2(bflo(tB2.y), bfhi(tB2.y));
  float2 fb10 = make_float2(bflo(tB2.z), bfhi(tB2.z)), fb11 = make_float2(bflo(tB2.w), bfhi(tB2.w));
  float2 fb12 = make_float2(bflo(tB3.x), bfhi(tB3.x)), fb13 = make_float2(bflo(tB3.y), bfhi(tB3.y));
  float2 fb14 = make_float2(bflo(tB3.z), bfhi(tB3.z)), fb15 = make_float2(bflo(tB3.w), bfhi(tB3.w));
#endif

  float a0i = start_w[2 * l] + start_b[2 * l];
  float a1i = start_w[2 * l + 1] + start_b[2 * l + 1];
  float m = fmaxf(a0i, a1i);
  #pragma unroll
  for (int s = 1; s < 64; s <<= 1) m = fmaxf(m, __shfl_xor(m, s, 64));
  float p0 = __expf(a0i - m), p1 = __expf(a1i - m);
  float tot = p0 + p1;
  #pragma unroll
  for (int s = 1; s < 64; s <<= 1) tot += __shfl_xor(tot, s, 64);
  float LLacc = m + __logf(tot);
  float inv = 1.0f / tot;
  uint ud = bfpack(p0 * inv, p1 * inv);

  uint qc0 = qtbl[(size_t)xrow[0] * 64 + l], qc1 = qtbl[(size_t)xrow[1] * 64 + l];
  uint qc2 = qtbl[(size_t)xrow[2] * 64 + l], qc3 = qtbl[(size_t)xrow[3] * 64 + l];
  uint qc4 = qtbl[(size_t)xrow[4] * 64 + l], qc5 = qtbl[(size_t)xrow[5] * 64 + l];
  uint qc6 = qtbl[(size_t)xrow[6] * 64 + l], qc7 = qtbl[(size_t)xrow[7] * 64 + l];
  int tk0 = xrow[8],  tk1 = xrow[9],  tk2 = xrow[10], tk3 = xrow[11];
  int tk4 = xrow[12], tk5 = xrow[13], tk6 = xrow[14], tk7 = xrow[15];

  for (int t8 = 0; t8 < 512; ++t8) {
    int tbase = t8 * 8;
    STEPF(0, 0) STEPF(1, 1) STEPF(2, 0) STEPF(3, 1)
    STEPF(4, 0) STEPF(5, 1) STEPF(6, 0) STEPF(7, 1)
  }
  if (l == 0 && wv == 0) chainLL[n] = LLacc;
}

// ---------- K4a: sum of Emax over all tokens ----------
__global__ __launch_bounds__(256) void k_emaxsum(const int* __restrict__ x,
    const float* __restrict__ Emax, float* __restrict__ sumE, int NT) {
  int idx = blockIdx.x * 256 + threadIdx.x;
  float s = 0.f;
  for (; idx < NT; idx += 128 * 256) s += Emax[x[idx]];
  #pragma unroll
  for (int mk = 1; mk < 64; mk <<= 1) s += __shfl_xor(s, mk, 64);
  if ((threadIdx.x & 63) == 0) atomicAdd(sumE, s);
}

// ---------- K4b: final scalar ----------
__global__ void k_final(const float* __restrict__ chainLL, const float* __restrict__ sumE,
                        float* __restrict__ out, int N) {
  int l = threadIdx.x;
  float v = (l < N) ? chainLL[l] : 0.f;
  #pragma unroll
  for (int mk = 1; mk < 64; mk <<= 1) v += __shfl_xor(v, mk, 64);
  if (l == 0) out[0] = -(v + sumE[0]) / (float)N;
}

extern "C" void kernel_launch(void* const* d_in, const int* in_sizes, int n_in,
                              void* d_out, int out_size, void* d_ws, size_t ws_size,
                              hipStream_t stream) {
  if (n_in < 6) return;
  const int*   x       = (const int*)d_in[0];
  const float* start_w = (const float*)d_in[1];
  const float* start_b = (const float*)d_in[2];
  const float* trans_w = (const float*)d_in[3];
  const float* emb_w   = (const float*)d_in[4];
  const float* vocab_w = (const float*)d_in[5];
  int NT = in_sizes[0];
  int N  = NT / 4096;
  int V  = in_sizes[5] / 128;

  char* ws = (char*)d_ws;
  float* S_glob  = (float*)(ws + 0);        // 128 f
  float* sumE    = (float*)(ws + 512);      // 1 f
  float* chainLL = (float*)(ws + 768);      // N f
  uint*  Tcol    = (uint*)(ws + 1024);      // 32 KB
  float* Emax    = (float*)(ws + 36864);    // V floats (ends 236864)
  uint*  qtbl    = (uint*)(ws + 262144);    // V*64 dwords = V*256 B
  size_t pst_off = 262144 + (size_t)V * 256;
  uint*  Pst     = (uint*)(ws + pst_off);   // N*8*8192 dwords
  size_t llseg_off = pst_off + (size_t)N * 8 * 8192 * 4;
  float* LLseg   = (float*)(ws + llseg_off);  // N*8*128 floats
  size_t need    = llseg_off + (size_t)N * 8 * 128 * 4 + 64;

  hipMemsetAsync(d_ws, 0, 1024, stream);
  k_tran<<<dim3(64), dim3(128), 0, stream>>>(trans_w, Tcol);
  k_logits<<<dim3((V + 63) / 64), dim3(256), 0, stream>>>(emb_w, vocab_w, qtbl, S_glob, V);
  k_qtab<<<dim3((V + 3) / 4), dim3(256), 0, stream>>>(qtbl, S_glob, Emax, V);
  if (ws_size >= need) {
    k_seg<<<dim3(N * 8), dim3(512), 0, stream>>>(x, Tcol, qtbl, Pst, LLseg);
    k_comb<<<dim3(N), dim3(256), 0, stream>>>(start_w, start_b, Pst, LLseg, chainLL);
  } else {
    k_chain<<<dim3(N), dim3(256), 0, stream>>>(x, start_w, start_b, Tcol, qtbl, chainLL);
  }
  k_emaxsum<<<dim3(128), dim3(256), 0, stream>>>(x, Emax, sumE, NT);
  k_final<<<dim3(1), dim3(64), 0, stream>>>(chainLL, sumE, (float*)d_out, N);
}

// Round 12
// 616.566 us; speedup vs baseline: 1.2068x; 1.1323x over previous
//
#include <hip/hip_runtime.h>

typedef unsigned int uint;
typedef unsigned short ushort;
typedef uint4 uint4_a __attribute__((may_alias));
typedef uint ui4v __attribute__((ext_vector_type(4)));
typedef float fx4 __attribute__((ext_vector_type(4)));
typedef short s8v __attribute__((ext_vector_type(8)));

// ---------- bf16 helpers ----------
__device__ __forceinline__ uint bfpack(float a, float b) {
  uint ua = __float_as_uint(a), ub = __float_as_uint(b);
  ua += 0x7fffu + ((ua >> 16) & 1u);   // RNE
  ub += 0x7fffu + ((ub >> 16) & 1u);
  return (ua >> 16) | (ub & 0xffff0000u);
}
__device__ __forceinline__ float bflo(uint d) { return __uint_as_float(d << 16); }
__device__ __forceinline__ float bfhi(uint d) { return __uint_as_float(d & 0xffff0000u); }
__device__ __forceinline__ ushort bfr(float s) {
  return (ushort)((__float_as_uint(s) + 0x8000u) >> 16);
}
__device__ __forceinline__ uint cvtpk(float a, float b) {
  uint r; asm("v_cvt_pk_bf16_f32 %0, %1, %2" : "=v"(r) : "v"(a), "v"(b)); return r;
}

#if __has_builtin(__builtin_amdgcn_fdot2_f32_bf16)
#define HAVE_BFDOT 1
typedef __bf16 v2bf __attribute__((ext_vector_type(2)));
__device__ __forceinline__ float dot2bf(uint a, uint b, float c) {
  return __builtin_amdgcn_fdot2_f32_bf16(__builtin_bit_cast(v2bf, a),
                                         __builtin_bit_cast(v2bf, b), c, false);
}
#else
#define HAVE_BFDOT 0
#endif

// ---------- shared MFMA helpers (fragment conventions verified by k_seg) ----------
#define REPB(M) M(0,0) M(0,1) M(0,2) M(0,3) M(1,0) M(1,1) M(1,2) M(1,3) \
                M(2,0) M(2,1) M(2,2) M(2,3) M(3,0) M(3,1) M(3,2) M(3,3) \
                M(4,0) M(4,1) M(4,2) M(4,3) M(5,0) M(5,1) M(5,2) M(5,3) \
                M(6,0) M(6,1) M(6,2) M(6,3) M(7,0) M(7,1) M(7,2) M(7,3)

#define MFMA(a, b, c) __builtin_amdgcn_mfma_f32_16x16x32_bf16( \
    __builtin_bit_cast(s8v, a), __builtin_bit_cast(s8v, b), c, 0, 0, 0)

// ---------- K1: transition table, column-pair layout (64 blocks) ----------
__global__ __launch_bounds__(128) void k_tran(const float* __restrict__ w,
                                              uint* __restrict__ Tcol) {
  __shared__ float rowLSE[128];
  int tid = threadIdx.x;
  const float4* w4 = (const float4*)(w + tid * 128);
  float se = 0.f;
  #pragma unroll 8
  for (int i = 0; i < 32; ++i) {
    float4 v = w4[i];
    se += __expf(v.x) + __expf(v.y) + __expf(v.z) + __expf(v.w);
  }
  rowLSE[tid] = __logf(se);
  __syncthreads();
  int j = tid & 63;
  int c = 2 * blockIdx.x + (tid >> 6);
  float a = __expf(w[(2 * j) * 128 + c]     - rowLSE[2 * j]);
  float b = __expf(w[(2 * j + 1) * 128 + c] - rowLSE[2 * j + 1]);
  Tcol[c * 64 + j] = bfpack(a, b);
}

// ---------- K1b: emb^T col-pair table for MFMA logits ----------
// Ecol[k*64 + dp] = bf16x2( emb[k][2dp], emb[k][2dp+1] )
__global__ __launch_bounds__(256) void k_epack(const float* __restrict__ emb,
                                               uint* __restrict__ Ecol) {
  int t = blockIdx.x * 256 + threadIdx.x;     // 8192 total
  if (t >= 8192) return;
  float2 e = *(const float2*)(emb + 2 * t);   // emb[k][2dp..2dp+1], k=t>>6 contiguous
  Ecol[t] = bfpack(e.x, e.y);
}

// ---------- K2a (MFMA): logits (bf16 pair layout) + per-k exp sums ----------
// C[v][k] tiles via 16x16x32 bf16 MFMA.  A = vocab rows (f32 -> bf16 pairs,
// same K-pair map p(d) as k_seg's verified LOADB), B = Ecol fragments
// (identical load pattern).  C layout (m89): row = 4*quad + reg, col = c.
__global__ __attribute__((amdgpu_flat_work_group_size(256, 256)))
void k_logits(const float* __restrict__ vocab, const uint* __restrict__ Ecol,
              uint* __restrict__ qtbl, float* __restrict__ S_glob, int V) {
  __shared__ float S_part[128];
  int tid = threadIdx.x, wv = tid >> 6, l = tid & 63, c = l & 15, quad = l >> 4;
  if (tid < 128) S_part[tid] = 0.f;
  __syncthreads();

  int vb = blockIdx.x * 64 + wv * 16;
  int vrow = vb + c; if (vrow > V - 1) vrow = V - 1;

  // B-frags (emb^T, static) -> AGPRs
  #define DECLE(kt, ks) ui4v eb##kt##_##ks;
  REPB(DECLE)
  {
    #define LOADE(kt, ks) { \
      const uint2* t2_ = (const uint2*)(Ecol + (size_t)(16 * (kt) + c) * 64 + 16 * (ks) + 2 * quad); \
      uint2 lo_ = t2_[0], hi_ = t2_[4]; \
      eb##kt##_##ks.x = lo_.x; eb##kt##_##ks.y = lo_.y; \
      eb##kt##_##ks.z = hi_.x; eb##kt##_##ks.w = hi_.y; }
    REPB(LOADE)
    #define PINE(kt, ks) asm volatile("" : "+a"(eb##kt##_##ks));
    REPB(PINE)
  }

  // A-frags: vocab row (v = vb + c), packed to bf16 pairs with map p(d)
  const float4* vr = (const float4*)(vocab + (size_t)vrow * 128);
  ui4v va0, va1, va2, va3;
  #define MKVA(ks, dst) { \
    float4 a_ = vr[8 * (ks) + quad]; \
    float4 b_ = vr[8 * (ks) + 4 + quad]; \
    dst.x = cvtpk(a_.x, a_.y); dst.y = cvtpk(a_.z, a_.w); \
    dst.z = cvtpk(b_.x, b_.y); dst.w = cvtpk(b_.z, b_.w); }
  MKVA(0, va0) MKVA(1, va1) MKVA(2, va2) MKVA(3, va3)

  fx4 zz4; zz4.x = 0.f; zz4.y = 0.f; zz4.z = 0.f; zz4.w = 0.f;
  #define CCKT(kt) \
    fx4 cc##kt = MFMA(va0, eb##kt##_0, zz4); \
    cc##kt = MFMA(va1, eb##kt##_1, cc##kt); \
    cc##kt = MFMA(va2, eb##kt##_2, cc##kt); \
    cc##kt = MFMA(va3, eb##kt##_3, cc##kt);
  CCKT(0) CCKT(1) CCKT(2) CCKT(3) CCKT(4) CCKT(5) CCKT(6) CCKT(7)

  int v0 = vb + 4 * quad;
  // per-k exp sums (guard pad rows)
  #define ESUM(kt) { \
    float se_ = 0.f; \
    if (v0 + 0 < V) se_ += __expf(cc##kt.x); \
    if (v0 + 1 < V) se_ += __expf(cc##kt.y); \
    if (v0 + 2 < V) se_ += __expf(cc##kt.z); \
    if (v0 + 3 < V) se_ += __expf(cc##kt.w); \
    atomicAdd(&S_part[16 * (kt) + c], se_); }
  ESUM(0) ESUM(1) ESUM(2) ESUM(3) ESUM(4) ESUM(5) ESUM(6) ESUM(7)

  // pack k-pairs (lanes c, c^1) and store qtbl[v*64 + j], j = 8kt + c/2
  #define STKT(kt) { \
    float nx_ = __shfl_xor(cc##kt.x, 1, 64); \
    float ny_ = __shfl_xor(cc##kt.y, 1, 64); \
    float nz_ = __shfl_xor(cc##kt.z, 1, 64); \
    float nw_ = __shfl_xor(cc##kt.w, 1, 64); \
    if (!(c & 1)) { \
      int j_ = 8 * (kt) + (c >> 1); \
      if (v0 + 0 < V) qtbl[(size_t)(v0 + 0) * 64 + j_] = bfpack(cc##kt.x, nx_); \
      if (v0 + 1 < V) qtbl[(size_t)(v0 + 1) * 64 + j_] = bfpack(cc##kt.y, ny_); \
      if (v0 + 2 < V) qtbl[(size_t)(v0 + 2) * 64 + j_] = bfpack(cc##kt.z, nz_); \
      if (v0 + 3 < V) qtbl[(size_t)(v0 + 3) * 64 + j_] = bfpack(cc##kt.w, nw_); \
    } }
  STKT(0) STKT(1) STKT(2) STKT(3) STKT(4) STKT(5) STKT(6) STKT(7)

  __syncthreads();
  if (tid < 128) atomicAdd(&S_glob[tid], S_part[tid]);
}

// ---------- K2c: in-place q[v][k] = exp(emis - Emax_v) (bf16), Emax table ----------
__global__ __launch_bounds__(256) void k_qtab(uint* __restrict__ qtbl,
    const float* __restrict__ S_glob, float* __restrict__ Emax, int V) {
  int tid = threadIdx.x;
  int l = tid & 63;
  int v = blockIdx.x * 4 + (tid >> 6);
  if (v >= V) return;
  float2 S2 = ((const float2*)S_glob)[l];
  float z0 = __logf(S2.x), z1 = __logf(S2.y);
  size_t off = (size_t)v * 64 + l;
  uint d = qtbl[off];
  float e0 = bflo(d) - z0, e1 = bfhi(d) - z1;
  float m = fmaxf(e0, e1);
  #pragma unroll
  for (int s = 1; s < 64; s <<= 1) m = fmaxf(m, __shfl_xor(m, s, 64));
  float q0 = __expf(e0 - m), q1 = __expf(e1 - m);
  qtbl[off] = bfpack(q0, q1);
  if (l == 0) Emax[v] = m;
}

// =====================================================================
// PHASE 1 (S-form, register-resident, stage-pipelined): R9-exact, 520us.
// 8 waves/block; wave wv owns S columns [16wv,16wv+16).  T^T frags in
// AGPRs; relabeled k-order -> C-output IS next B-fragment after
// scale+cvt_pk.  Rescale every 4th fold (guarded).  PLATEAU: MFMA pipe
// 51% busy (per-SIMD 19.4cyc/MFMA x 64/fold-pair = demand), VALU 15%,
// idle ~34% = per-wave dep stalls; 2 waves/SIMD reg-capped (128V+128A).
// =====================================================================
#define MST0(OUT, BN) \
  OUT##0 = MFMA(tb0_0, BN, zz4); OUT##1 = MFMA(tb1_0, BN, zz4); \
  OUT##2 = MFMA(tb2_0, BN, zz4); OUT##3 = MFMA(tb3_0, BN, zz4); \
  OUT##4 = MFMA(tb4_0, BN, zz4); OUT##5 = MFMA(tb5_0, BN, zz4); \
  OUT##6 = MFMA(tb6_0, BN, zz4); OUT##7 = MFMA(tb7_0, BN, zz4);
#define MSTA(OUT, BN, ks) \
  OUT##0 = MFMA(tb0_##ks, BN, OUT##0); OUT##1 = MFMA(tb1_##ks, BN, OUT##1); \
  OUT##2 = MFMA(tb2_##ks, BN, OUT##2); OUT##3 = MFMA(tb3_##ks, BN, OUT##3); \
  OUT##4 = MFMA(tb4_##ks, BN, OUT##4); OUT##5 = MFMA(tb5_##ks, BN, OUT##5); \
  OUT##6 = MFMA(tb6_##ks, BN, OUT##6); OUT##7 = MFMA(tb7_##ks, BN, OUT##7);

#define PKPAIR(CCA, CCB, QA, QB, DOUT) { \
  float f0 = bflo(QA.x) * rs, f1 = bfhi(QA.x) * rs; \
  float f2 = bflo(QA.y) * rs, f3 = bfhi(QA.y) * rs; \
  float s0 = CCA.x * f0, s1 = CCA.y * f1, s2 = CCA.z * f2, s3 = CCA.w * f3; \
  fm = fmaxf(fm, fmaxf(fmaxf(s0, s1), fmaxf(s2, s3))); \
  uint p0, p1, p2, p3; \
  asm("v_cvt_pk_bf16_f32 %0, %1, %2" : "=v"(p0) : "v"(s0), "v"(s1)); \
  asm("v_cvt_pk_bf16_f32 %0, %1, %2" : "=v"(p1) : "v"(s2), "v"(s3)); \
  float g0 = bflo(QB.x) * rs, g1 = bfhi(QB.x) * rs; \
  float g2 = bflo(QB.y) * rs, g3 = bfhi(QB.y) * rs; \
  float t0 = CCB.x * g0, t1 = CCB.y * g1, t2 = CCB.z * g2, t3 = CCB.w * g3; \
  fm = fmaxf(fm, fmaxf(fmaxf(t0, t1), fmaxf(t2, t3))); \
  asm("v_cvt_pk_bf16_f32 %0, %1, %2" : "=v"(p2) : "v"(t0), "v"(t1)); \
  asm("v_cvt_pk_bf16_f32 %0, %1, %2" : "=v"(p3) : "v"(t2), "v"(t3)); \
  DOUT.x = p0; DOUT.y = p1; DOUT.z = p2; DOUT.w = p3; }

#define PKPAIR_NR(CCA, CCB, QA, QB, DOUT) { \
  float s0 = CCA.x * bflo(QA.x), s1 = CCA.y * bfhi(QA.x); \
  float s2 = CCA.z * bflo(QA.y), s3 = CCA.w * bfhi(QA.y); \
  uint p0, p1, p2, p3; \
  asm("v_cvt_pk_bf16_f32 %0, %1, %2" : "=v"(p0) : "v"(s0), "v"(s1)); \
  asm("v_cvt_pk_bf16_f32 %0, %1, %2" : "=v"(p1) : "v"(s2), "v"(s3)); \
  float t0 = CCB.x * bflo(QB.x), t1 = CCB.y * bfhi(QB.x); \
  float t2 = CCB.z * bflo(QB.y), t3 = CCB.w * bfhi(QB.y); \
  asm("v_cvt_pk_bf16_f32 %0, %1, %2" : "=v"(p2) : "v"(t0), "v"(t1)); \
  asm("v_cvt_pk_bf16_f32 %0, %1, %2" : "=v"(p3) : "v"(t2), "v"(t3)); \
  DOUT.x = p0; DOUT.y = p1; DOUT.z = p2; DOUT.w = p3; }

#define QLD(dst, tk, i) dst = *(const uint2*)(qtbl + ((size_t)(tk) << 6) + 8 * (i) + 2 * quad);

#define QRELOAD(Q, TKREG, FBASE) \
  QLD(Q##0, TKREG, 0) QLD(Q##1, TKREG, 1) QLD(Q##2, TKREG, 2) QLD(Q##3, TKREG, 3) \
  QLD(Q##4, TKREG, 4) QLD(Q##5, TKREG, 5) QLD(Q##6, TKREG, 6) QLD(Q##7, TKREG, 7) \
  { int fi_ = (FBASE) + 4; if (fi_ > 511) fi_ = 511; TKREG = xseg[fi_]; }

#define SLOT_RS(CIN, COUT, Q, TKREG, FBASE) { \
  rs = 1.0f / fmA;  llacc += __log2f(fmA); \
  float fm = 0.f; \
  PKPAIR(CIN##0, CIN##1, Q##0, Q##1, Bs0) \
  MST0(COUT, Bs0) \
  PKPAIR(CIN##2, CIN##3, Q##2, Q##3, Bs1) \
  MSTA(COUT, Bs1, 1) \
  PKPAIR(CIN##4, CIN##5, Q##4, Q##5, Bs2) \
  MSTA(COUT, Bs2, 2) \
  PKPAIR(CIN##6, CIN##7, Q##6, Q##7, Bs3) \
  MSTA(COUT, Bs3, 3) \
  QRELOAD(Q, TKREG, FBASE) \
  fm = fmaxf(fm, __shfl_xor(fm, 16, 64)); \
  fm = fmaxf(fm, __shfl_xor(fm, 32, 64)); \
  fmA = fmaxf(fm, 1e-33f); \
}

#define SLOT_NR(CIN, COUT, Q, TKREG, FBASE) { \
  PKPAIR_NR(CIN##0, CIN##1, Q##0, Q##1, Bs0) \
  MST0(COUT, Bs0) \
  PKPAIR_NR(CIN##2, CIN##3, Q##2, Q##3, Bs1) \
  MSTA(COUT, Bs1, 1) \
  PKPAIR_NR(CIN##4, CIN##5, Q##4, Q##5, Bs2) \
  MSTA(COUT, Bs2, 2) \
  PKPAIR_NR(CIN##6, CIN##7, Q##6, Q##7, Bs3) \
  MSTA(COUT, Bs3, 3) \
  QRELOAD(Q, TKREG, FBASE) \
}

__global__ __attribute__((amdgpu_flat_work_group_size(512, 512), amdgpu_waves_per_eu(2)))
void k_seg(const int* __restrict__ x, const uint* __restrict__ Tcol,
           const uint* __restrict__ qtbl, uint* __restrict__ Pst,
           float* __restrict__ LLseg) {
  int tid = threadIdx.x;
  int wv = tid >> 6, l = tid & 63, c = l & 15, quad = l >> 4;
  int blk = blockIdx.x;
  const int* xseg = x + (size_t)(blk >> 3) * 4096 + (size_t)(blk & 7) * 512;

  #define DECLB(nt, ks) ui4v tb##nt##_##ks;
  REPB(DECLB)
  {
    #define LOADB(nt, ks) { \
      const uint2* t2_ = (const uint2*)(Tcol + (size_t)(16 * (nt) + c) * 64 + 16 * (ks) + 2 * quad); \
      uint2 lo_ = t2_[0], hi_ = t2_[4]; \
      tb##nt##_##ks.x = lo_.x; tb##nt##_##ks.y = lo_.y; \
      tb##nt##_##ks.z = hi_.x; tb##nt##_##ks.w = hi_.y; }
    REPB(LOADB)
    #define PINB(nt, ks) asm volatile("" : "+a"(tb##nt##_##ks));
    REPB(PINB)
  }

  ui4v Bs0, Bs1, Bs2, Bs3;
  {
    uint iv = (quad == (c >> 2)) ? (0x3F80u << (16 * (c & 1))) : 0u;
    int dsel = ((c >> 1) & 1) + 2 * (wv & 1);
    int kssel = wv >> 1;
    Bs0.x = (kssel == 0 && dsel == 0) ? iv : 0u;
    Bs0.y = (kssel == 0 && dsel == 1) ? iv : 0u;
    Bs0.z = (kssel == 0 && dsel == 2) ? iv : 0u;
    Bs0.w = (kssel == 0 && dsel == 3) ? iv : 0u;
    Bs1.x = (kssel == 1 && dsel == 0) ? iv : 0u;
    Bs1.y = (kssel == 1 && dsel == 1) ? iv : 0u;
    Bs1.z = (kssel == 1 && dsel == 2) ? iv : 0u;
    Bs1.w = (kssel == 1 && dsel == 3) ? iv : 0u;
    Bs2.x = (kssel == 2 && dsel == 0) ? iv : 0u;
    Bs2.y = (kssel == 2 && dsel == 1) ? iv : 0u;
    Bs2.z = (kssel == 2 && dsel == 2) ? iv : 0u;
    Bs2.w = (kssel == 2 && dsel == 3) ? iv : 0u;
    Bs3.x = (kssel == 3 && dsel == 0) ? iv : 0u;
    Bs3.y = (kssel == 3 && dsel == 1) ? iv : 0u;
    Bs3.z = (kssel == 3 && dsel == 2) ? iv : 0u;
    Bs3.w = (kssel == 3 && dsel == 3) ? iv : 0u;
  }

  float rs = 1.0f, llacc = 0.0f, fmA = 1.0f;
  fx4 zz4; zz4.x = 0.f; zz4.y = 0.f; zz4.z = 0.f; zz4.w = 0.f;

  fx4 cA0, cA1, cA2, cA3, cA4, cA5, cA6, cA7;
  fx4 cB0, cB1, cB2, cB3, cB4, cB5, cB6, cB7;

  int tk0 = xseg[0], tk1 = xseg[1];
  int tkA = xseg[2], tkB = xseg[3];
  uint2 qc0, qc1, qc2, qc3, qc4, qc5, qc6, qc7;
  uint2 qn0, qn1, qn2, qn3, qn4, qn5, qn6, qn7;
  QLD(qc0, tk0, 0) QLD(qc1, tk0, 1) QLD(qc2, tk0, 2) QLD(qc3, tk0, 3)
  QLD(qc4, tk0, 4) QLD(qc5, tk0, 5) QLD(qc6, tk0, 6) QLD(qc7, tk0, 7)
  QLD(qn0, tk1, 0) QLD(qn1, tk1, 1) QLD(qn2, tk1, 2) QLD(qn3, tk1, 3)
  QLD(qn4, tk1, 4) QLD(qn5, tk1, 5) QLD(qn6, tk1, 6) QLD(qn7, tk1, 7)

  MST0(cA, Bs0) MSTA(cA, Bs1, 1) MSTA(cA, Bs2, 2) MSTA(cA, Bs3, 3)

  if (wv & 1) __builtin_amdgcn_s_sleep(8);

  for (int f4 = 0; f4 < 128; ++f4) {
    int f = f4 * 4;
    SLOT_RS(cA, cB, qc, tkA, f)
    SLOT_NR(cB, cA, qn, tkB, f + 1)
    SLOT_NR(cA, cB, qc, tkA, f + 2)
    SLOT_NR(cB, cA, qn, tkB, f + 3)
  }

  size_t pb = (size_t)blk * 8192 + (size_t)(16 * wv + c) * 64;
  uint2 st;
  st.x = Bs0.x; st.y = Bs0.y; *(uint2*)(Pst + pb +  0 + 2 * quad) = st;
  st.x = Bs0.z; st.y = Bs0.w; *(uint2*)(Pst + pb +  8 + 2 * quad) = st;
  st.x = Bs1.x; st.y = Bs1.y; *(uint2*)(Pst + pb + 16 + 2 * quad) = st;
  st.x = Bs1.z; st.y = Bs1.w; *(uint2*)(Pst + pb + 24 + 2 * quad) = st;
  st.x = Bs2.x; st.y = Bs2.y; *(uint2*)(Pst + pb + 32 + 2 * quad) = st;
  st.x = Bs2.z; st.y = Bs2.w; *(uint2*)(Pst + pb + 40 + 2 * quad) = st;
  st.x = Bs3.x; st.y = Bs3.y; *(uint2*)(Pst + pb + 48 + 2 * quad) = st;
  st.x = Bs3.z; st.y = Bs3.w; *(uint2*)(Pst + pb + 56 + 2 * quad) = st;
  if (quad == 0)
    LLseg[(size_t)blk * 128 + 16 * wv + c] = llacc * 0.6931471805599453f;
}

// =====================================================================
// PHASE 2 (4-wave): per chain, alpha0 -> fold 8 segment matrices.
// =====================================================================
__global__ __launch_bounds__(256, 1) void k_comb(
    const float* __restrict__ start_w, const float* __restrict__ start_b,
    const uint* __restrict__ Pst, const float* __restrict__ LLseg,
    float* __restrict__ chainLL) {
  __shared__ uint al[64] __attribute__((aligned(16)));
  __shared__ float2 part[4][64];
  int n = blockIdx.x, tid = threadIdx.x;
  int wv = tid >> 6, l = tid & 63;
  float p0 = 0.f, p1 = 0.f, LLacc = 0.f;
  if (wv == 0) {
    float a0i = start_w[2 * l] + start_b[2 * l];
    float a1i = start_w[2 * l + 1] + start_b[2 * l + 1];
    float m = fmaxf(a0i, a1i);
    #pragma unroll
    for (int s = 1; s < 64; s <<= 1) m = fmaxf(m, __shfl_xor(m, s, 64));
    p0 = __expf(a0i - m); p1 = __expf(a1i - m);
    float tot = p0 + p1;
    #pragma unroll
    for (int s = 1; s < 64; s <<= 1) tot += __shfl_xor(tot, s, 64);
    LLacc = m + __logf(tot);
    float inv = 1.0f / tot;
    p0 *= inv; p1 *= inv;
  }
  const uint4_a* u4 = (const uint4_a*)al;

  for (int s = 0; s < 8; ++s) {
    float g = 0.f;
    if (wv == 0) {
      float La = LLseg[(size_t)(n * 8 + s) * 128 + 2 * l];
      float Lb = LLseg[(size_t)(n * 8 + s) * 128 + 2 * l + 1];
      g = fmaxf(La, Lb);
      #pragma unroll
      for (int sh = 1; sh < 64; sh <<= 1) g = fmaxf(g, __shfl_xor(g, sh, 64));
      al[l] = bfpack(p0 * __expf(La - g), p1 * __expf(Lb - g));
    }
    __syncthreads();

    const uint* pb = Pst + (size_t)(n * 8 + s) * 8192;
    float o0 = 0.f, o1 = 0.f;
    #pragma unroll
    for (int ii = 0; ii < 4; ++ii) {
      int i = 4 * wv + ii;
      uint4 uu = u4[i];
      #pragma unroll
      for (int d = 0; d < 4; ++d) {
        uint ad = (d == 0) ? uu.x : (d == 1) ? uu.y : (d == 2) ? uu.z : uu.w;
        uint P0 = pb[(8 * i + 2 * d) * 64 + l];
        uint P1 = pb[(8 * i + 2 * d + 1) * 64 + l];
        float alo = bflo(ad), ahi = bfhi(ad);
        o0 = fmaf(alo, bflo(P0), o0); o0 = fmaf(ahi, bflo(P1), o0);
        o1 = fmaf(alo, bfhi(P0), o1); o1 = fmaf(ahi, bfhi(P1), o1);
      }
    }
    part[wv][l] = make_float2(o0, o1);
    __syncthreads();

    if (wv == 0) {
      float2 x0 = part[0][l], x1 = part[1][l], x2 = part[2][l], x3 = part[3][l];
      float s0 = (x0.x + x1.x) + (x2.x + x3.x);
      float s1 = (x0.y + x1.y) + (x2.y + x3.y);
      float tt = s0 + s1;
      #pragma unroll
      for (int sh = 1; sh < 64; sh <<= 1) tt += __shfl_xor(tt, sh, 64);
      LLacc += g + __logf(tt);
      float it = 1.0f / tt;
      p0 = s0 * it; p1 = s1 * it;
    }
  }
  if (tid == 0) chainLL[n] = LLacc;
}

// =====================================================================
// FALLBACK: sequential scan, 4 waves per chain — used if ws too small
// =====================================================================
#define RLU(i) ((uint)__builtin_amdgcn_readlane((int)ud, rbase + (i)))
#if HAVE_BFDOT
#define DOTS \
  uint u0=RLU(0),u1=RLU(1),u2=RLU(2),u3=RLU(3),u4=RLU(4),u5=RLU(5),u6=RLU(6),u7=RLU(7), \
       u8=RLU(8),u9=RLU(9),u10=RLU(10),u11=RLU(11),u12=RLU(12),u13=RLU(13),u14=RLU(14),u15=RLU(15); \
  float A0 = dot2bf(u0, tA0.x, 0.f), A1 = dot2bf(u1, tA0.y, 0.f); \
  float A2 = dot2bf(u2, tA0.z, 0.f), A3 = dot2bf(u3, tA0.w, 0.f); \
  float B0 = dot2bf(u0, tB0.x, 0.f), B1 = dot2bf(u1, tB0.y, 0.f); \
  float B2 = dot2bf(u2, tB0.z, 0.f), B3 = dot2bf(u3, tB0.w, 0.f); \
  A0 = dot2bf(u4, tA1.x, A0); A1 = dot2bf(u5, tA1.y, A1); \
  A2 = dot2bf(u6, tA1.z, A2); A3 = dot2bf(u7, tA1.w, A3); \
  B0 = dot2bf(u4, tB1.x, B0); B1 = dot2bf(u5, tB1.y, B1); \
  B2 = dot2bf(u6, tB1.z, B2); B3 = dot2bf(u7, tB1.w, B3); \
  A0 = dot2bf(u8, tA2.x, A0); A1 = dot2bf(u9, tA2.y, A1); \
  A2 = dot2bf(u10, tA2.z, A2); A3 = dot2bf(u11, tA2.w, A3); \
  B0 = dot2bf(u8, tB2.x, B0); B1 = dot2bf(u9, tB2.y, B1); \
  B2 = dot2bf(u10, tB2.z, B2); B3 = dot2bf(u11, tB2.w, B3); \
  A0 = dot2bf(u12, tA3.x, A0); A1 = dot2bf(u13, tA3.y, A1); \
  A2 = dot2bf(u14, tA3.z, A2); A3 = dot2bf(u15, tA3.w, A3); \
  B0 = dot2bf(u12, tB3.x, B0); B1 = dot2bf(u13, tB3.y, B1); \
  B2 = dot2bf(u14, tB3.z, B2); B3 = dot2bf(u15, tB3.w, B3); \
  float Asum = (A0 + A1) + (A2 + A3), Bsum = (B0 + B1) + (B2 + B3);
#else
#define ACC2(i, AA, BB) { uint tu = RLU(i); float lo = bflo(tu), hi = bfhi(tu); \
  AA += lo * fa##i.x; AA += hi * fa##i.y; BB += lo * fb##i.x; BB += hi * fb##i.y; }
#define DOTS \
  float A0 = 0.f, A1 = 0.f, A2 = 0.f, A3 = 0.f; \
  float B0 = 0.f, B1 = 0.f, B2 = 0.f, B3 = 0.f; \
  ACC2(0, A0, B0) ACC2(1, A1, B1) ACC2(2, A2, B2) ACC2(3, A3, B3) \
  ACC2(4, A0, B0) ACC2(5, A1, B1) ACC2(6, A2, B2) ACC2(7, A3, B3) \
  ACC2(8, A0, B0) ACC2(9, A1, B1) ACC2(10, A2, B2) ACC2(11, A3, B3) \
  ACC2(12, A0, B0) ACC2(13, A1, B1) ACC2(14, A2, B2) ACC2(15, A3, B3) \
  float Asum = (A0 + A1) + (A2 + A3), Bsum = (B0 + B1) + (B2 + B3);
#endif

#define STEPF(j, p) { \
  DOTS \
  *(float2*)&partLDS[(p) * 640 + l * 10 + 2 * wv] = make_float2(Asum, Bsum); \
  asm volatile("s_waitcnt lgkmcnt(0)\ns_barrier" ::: "memory"); \
  const float2* pr = (const float2*)&partLDS[(p) * 640 + l * 10]; \
  float2 x0 = pr[0], x1 = pr[1], x2 = pr[2], x3 = pr[3]; \
  float s0 = (x0.x + x1.x) + (x2.x + x3.x); \
  float s1 = (x0.y + x1.y) + (x2.y + x3.y); \
  float nu0 = s0 * bflo(qc##j), nu1 = s1 * bfhi(qc##j); \
  qc##j = qtbl[(size_t)tk##j * 64 + l]; \
  tk##j = xrow[(tbase + (j) + 16) & 4095]; \
  if ((j) == 7) { \
    float tt = nu0 + nu1; \
    for (int s = 1; s < 64; s <<= 1) tt += __shfl_xor(tt, s, 64); \
    LLacc += __logf(tt); \
    float it = 1.0f / tt; nu0 *= it; nu1 *= it; \
  } \
  ud = bfpack(nu0, nu1); }

__global__ __launch_bounds__(256, 1) void k_chain(const int* __restrict__ x,
    const float* __restrict__ start_w, const float* __restrict__ start_b,
    const uint* __restrict__ Tcol, const uint* __restrict__ qtbl,
    float* __restrict__ chainLL) {
  __shared__ float partLDS[1280];
  int n = blockIdx.x;
  int l = threadIdx.x & 63;
  int wv = __builtin_amdgcn_readfirstlane((int)(threadIdx.x >> 6));
  int rbase = wv * 16;
  const int* xrow = x + (size_t)n * 4096;

  const uint4* ca = (const uint4*)(Tcol + (2 * l) * 64 + rbase);
  const uint4* cb = (const uint4*)(Tcol + (2 * l + 1) * 64 + rbase);
  uint4 tA0 = ca[0], tA1 = ca[1], tA2 = ca[2], tA3 = ca[3];
  uint4 tB0 = cb[0], tB1 = cb[1], tB2 = cb[2], tB3 = cb[3];
#if !HAVE_BFDOT
  float2 fa0 = make_float2(bflo(tA0.x), bfhi(tA0.x)), fa1 = make_float2(bflo(tA0.y), bfhi(tA0.y));
  float2 fa2 = make_float2(bflo(tA0.z), bfhi(tA0.z)), fa3 = make_float2(bflo(tA0.w), bfhi(tA0.w));
  float2 fa4 = make_float2(bflo(tA1.x), bfhi(tA1.x)), fa5 = make_float2(bflo(tA1.y), bfhi(tA1.y));
  float2 fa6 = make_float2(bflo(tA1.z), bfhi(tA1.z)), fa7 = make_float2(bflo(tA1.w), bfhi(tA1.w));
  float2 fa8 = make_float2(bflo(tA2.x), bfhi(tA2.x)), fa9 = make_float2(bflo(tA2.y), bfhi(tA2.y));
  float2 fa10 = make_float2(bflo(tA2.z), bfhi(tA2.z)), fa11 = make_float2(bflo(tA2.w), bfhi(tA2.w));
  float2 fa12 = make_float2(bflo(tA3.x), bfhi(tA3.x)), fa13 = make_float2(bflo(tA3.y), bfhi(tA3.y));
  float2 fa14 = make_float2(bflo(tA3.z), bfhi(tA3.z)), fa15 = make_float2(bflo(tA3.w), bfhi(tA3.w));
  float2 fb0 = make_float2(bflo(tB0.x), bfhi(tB0.x)), fb1 = make_float2(bflo(tB0.y), bfhi(tB0.y));
  float2 fb2 = make_float2(bflo(tB0.z), bfhi(tB0.z)), fb3 = make_float2(bflo(tB0.w), bfhi(tB0.w));
  float2 fb4 = make_float2(bflo(tB1.x), bfhi(tB1.x)), fb5 = make_float2(bflo(tB1.y), bfhi(tB1.y));
  float2 fb6 = make_float2(bflo(tB1.z), bfhi(tB1.z)), fb7 = make_float2(bflo(tB1.w), bfhi(tB1.w));
  float2 fb8 = make_float2(bflo(tB2.x), bfhi(tB2.x)), fb9 = make_float2(bflo(tB2.y), bfhi(tB2.y));
  float2 fb10 = make_float2(bflo(tB2.z), bfhi(tB2.z)), fb11 = make_float2(bflo(tB2.w), bfhi(tB2.w));
  float2 fb12 = make_float2(bflo(tB3.x), bfhi(tB3.x)), fb13 = make_float2(bflo(tB3.y), bfhi(tB3.y));
  float2 fb14 = make_float2(bflo(tB3.z), bfhi(tB3.z)), fb15 = make_float2(bflo(tB3.w), bfhi(tB3.w));
#endif

  float a0i = start_w[2 * l] + start_b[2 * l];
  float a1i = start_w[2 * l + 1] + start_b[2 * l + 1];
  float m = fmaxf(a0i, a1i);
  #pragma unroll
  for (int s = 1; s < 64; s <<= 1) m = fmaxf(m, __shfl_xor(m, s, 64));
  float p0 = __expf(a0i - m), p1 = __expf(a1i - m);
  float tot = p0 + p1;
  #pragma unroll
  for (int s = 1; s < 64; s <<= 1) tot += __shfl_xor(tot, s, 64);
  float LLacc = m + __logf(tot);
  float inv = 1.0f / tot;
  uint ud = bfpack(p0 * inv, p1 * inv);

  uint qc0 = qtbl[(size_t)xrow[0] * 64 + l], qc1 = qtbl[(size_t)xrow[1] * 64 + l];
  uint qc2 = qtbl[(size_t)xrow[2] * 64 + l], qc3 = qtbl[(size_t)xrow[3] * 64 + l];
  uint qc4 = qtbl[(size_t)xrow[4] * 64 + l], qc5 = qtbl[(size_t)xrow[5] * 64 + l];
  uint qc6 = qtbl[(size_t)xrow[6] * 64 + l], qc7 = qtbl[(size_t)xrow[7] * 64 + l];
  int tk0 = xrow[8],  tk1 = xrow[9],  tk2 = xrow[10], tk3 = xrow[11];
  int tk4 = xrow[12], tk5 = xrow[13], tk6 = xrow[14], tk7 = xrow[15];

  for (int t8 = 0; t8 < 512; ++t8) {
    int tbase = t8 * 8;
    STEPF(0, 0) STEPF(1, 1) STEPF(2, 0) STEPF(3, 1)
    STEPF(4, 0) STEPF(5, 1) STEPF(6, 0) STEPF(7, 1)
  }
  if (l == 0 && wv == 0) chainLL[n] = LLacc;
}

// ---------- K4a: sum of Emax over all tokens ----------
__global__ __launch_bounds__(256) void k_emaxsum(const int* __restrict__ x,
    const float* __restrict__ Emax, float* __restrict__ sumE, int NT) {
  int idx = blockIdx.x * 256 + threadIdx.x;
  float s = 0.f;
  for (; idx < NT; idx += 128 * 256) s += Emax[x[idx]];
  #pragma unroll
  for (int mk = 1; mk < 64; mk <<= 1) s += __shfl_xor(s, mk, 64);
  if ((threadIdx.x & 63) == 0) atomicAdd(sumE, s);
}

// ---------- K4b: final scalar ----------
__global__ void k_final(const float* __restrict__ chainLL, const float* __restrict__ sumE,
                        float* __restrict__ out, int N) {
  int l = threadIdx.x;
  float v = (l < N) ? chainLL[l] : 0.f;
  #pragma unroll
  for (int mk = 1; mk < 64; mk <<= 1) v += __shfl_xor(v, mk, 64);
  if (l == 0) out[0] = -(v + sumE[0]) / (float)N;
}

extern "C" void kernel_launch(void* const* d_in, const int* in_sizes, int n_in,
                              void* d_out, int out_size, void* d_ws, size_t ws_size,
                              hipStream_t stream) {
  if (n_in < 6) return;
  const int*   x       = (const int*)d_in[0];
  const float* start_w = (const float*)d_in[1];
  const float* start_b = (const float*)d_in[2];
  const float* trans_w = (const float*)d_in[3];
  const float* emb_w   = (const float*)d_in[4];
  const float* vocab_w = (const float*)d_in[5];
  int NT = in_sizes[0];
  int N  = NT / 4096;
  int V  = in_sizes[5] / 128;

  char* ws = (char*)d_ws;
  float* S_glob  = (float*)(ws + 0);        // 128 f
  float* sumE    = (float*)(ws + 512);      // 1 f
  float* chainLL = (float*)(ws + 768);      // N f
  uint*  Tcol    = (uint*)(ws + 1024);      // 32 KB (ends 33792)
  uint*  Ecol    = (uint*)(ws + 36864);     // 32 KB (ends 69632)
  float* Emax    = (float*)(ws + 73728);    // V floats (ends 73728+4V)
  size_t qtbl_off = 73728 + (size_t)V * 4;
  qtbl_off = (qtbl_off + 255) & ~(size_t)255;
  uint*  qtbl    = (uint*)(ws + qtbl_off);  // V*64 dwords
  size_t pst_off = qtbl_off + (size_t)V * 256;
  uint*  Pst     = (uint*)(ws + pst_off);   // N*8*8192 dwords
  size_t llseg_off = pst_off + (size_t)N * 8 * 8192 * 4;
  float* LLseg   = (float*)(ws + llseg_off);  // N*8*128 floats
  size_t need    = llseg_off + (size_t)N * 8 * 128 * 4 + 64;

  hipMemsetAsync(d_ws, 0, 1024, stream);
  k_tran<<<dim3(64), dim3(128), 0, stream>>>(trans_w, Tcol);
  k_epack<<<dim3(32), dim3(256), 0, stream>>>(emb_w, Ecol);
  k_logits<<<dim3((V + 63) / 64), dim3(256), 0, stream>>>(vocab_w, Ecol, qtbl, S_glob, V);
  k_qtab<<<dim3((V + 3) / 4), dim3(256), 0, stream>>>(qtbl, S_glob, Emax, V);
  if (ws_size >= need) {
    k_seg<<<dim3(N * 8), dim3(512), 0, stream>>>(x, Tcol, qtbl, Pst, LLseg);
    k_comb<<<dim3(N), dim3(256), 0, stream>>>(start_w, start_b, Pst, LLseg, chainLL);
  } else {
    k_chain<<<dim3(N), dim3(256), 0, stream>>>(x, start_w, start_b, Tcol, qtbl, chainLL);
  }
  k_emaxsum<<<dim3(128), dim3(256), 0, stream>>>(x, Emax, sumE, NT);
  k_final<<<dim3(1), dim3(64), 0, stream>>>(chainLL, sumE, (float*)d_out, N);
}

// Round 13
// 604.082 us; speedup vs baseline: 1.2317x; 1.0207x over previous
//
#include <hip/hip_runtime.h>

typedef unsigned int uint;
typedef unsigned short ushort;
typedef uint4 uint4_a __attribute__((may_alias));
typedef uint ui4v __attribute__((ext_vector_type(4)));
typedef float fx4 __attribute__((ext_vector_type(4)));
typedef short s8v __attribute__((ext_vector_type(8)));

// ---------- bf16 helpers ----------
__device__ __forceinline__ uint bfpack(float a, float b) {
  uint ua = __float_as_uint(a), ub = __float_as_uint(b);
  ua += 0x7fffu + ((ua >> 16) & 1u);   // RNE
  ub += 0x7fffu + ((ub >> 16) & 1u);
  return (ua >> 16) | (ub & 0xffff0000u);
}
__device__ __forceinline__ float bflo(uint d) { return __uint_as_float(d << 16); }
__device__ __forceinline__ float bfhi(uint d) { return __uint_as_float(d & 0xffff0000u); }
__device__ __forceinline__ ushort bfr(float s) {
  return (ushort)((__float_as_uint(s) + 0x8000u) >> 16);
}
__device__ __forceinline__ uint cvtpk(float a, float b) {
  uint r; asm("v_cvt_pk_bf16_f32 %0, %1, %2" : "=v"(r) : "v"(a), "v"(b)); return r;
}

#if __has_builtin(__builtin_amdgcn_fdot2_f32_bf16)
#define HAVE_BFDOT 1
typedef __bf16 v2bf __attribute__((ext_vector_type(2)));
__device__ __forceinline__ float dot2bf(uint a, uint b, float c) {
  return __builtin_amdgcn_fdot2_f32_bf16(__builtin_bit_cast(v2bf, a),
                                         __builtin_bit_cast(v2bf, b), c, false);
}
#else
#define HAVE_BFDOT 0
#endif

// ---------- shared MFMA helpers (fragment conventions verified by k_seg) ----------
#define REPB(M) M(0,0) M(0,1) M(0,2) M(0,3) M(1,0) M(1,1) M(1,2) M(1,3) \
                M(2,0) M(2,1) M(2,2) M(2,3) M(3,0) M(3,1) M(3,2) M(3,3) \
                M(4,0) M(4,1) M(4,2) M(4,3) M(5,0) M(5,1) M(5,2) M(5,3) \
                M(6,0) M(6,1) M(6,2) M(6,3) M(7,0) M(7,1) M(7,2) M(7,3)

#define MFMA(a, b, c) __builtin_amdgcn_mfma_f32_16x16x32_bf16( \
    __builtin_bit_cast(s8v, a), __builtin_bit_cast(s8v, b), c, 0, 0, 0)

// ---------- K1 (merged): blocks <64 -> Tcol column pairs; >=64 -> Ecol pack ----------
// Tcol[c*64 + j] = bf16x2( exp(tran[2j][c]), exp(tran[2j+1][c]) )
// Ecol[k*64 + dp] = bf16x2( emb[k][2dp], emb[k][2dp+1] )
__global__ __launch_bounds__(128) void k_prep(const float* __restrict__ w,
                                              const float* __restrict__ emb,
                                              uint* __restrict__ Tcol,
                                              uint* __restrict__ Ecol) {
  int blk = blockIdx.x, tid = threadIdx.x;
  if (blk < 64) {
    __shared__ float rowLSE[128];
    const float4* w4 = (const float4*)(w + tid * 128);
    float se = 0.f;
    #pragma unroll 8
    for (int i = 0; i < 32; ++i) {
      float4 v = w4[i];
      se += __expf(v.x) + __expf(v.y) + __expf(v.z) + __expf(v.w);
    }
    rowLSE[tid] = __logf(se);
    __syncthreads();
    int j = tid & 63;
    int c = 2 * blk + (tid >> 6);
    float a = __expf(w[(2 * j) * 128 + c]     - rowLSE[2 * j]);
    float b = __expf(w[(2 * j + 1) * 128 + c] - rowLSE[2 * j + 1]);
    Tcol[c * 64 + j] = bfpack(a, b);
  } else {
    int t = (blk - 64) * 128 + tid;          // 64 blocks x 128 = 8192
    float2 e = *(const float2*)(emb + 2 * t);
    Ecol[t] = bfpack(e.x, e.y);
  }
}

// ---------- K2a (MFMA): logits (bf16 pair layout) + per-k exp sums ----------
__global__ __attribute__((amdgpu_flat_work_group_size(256, 256)))
void k_logits(const float* __restrict__ vocab, const uint* __restrict__ Ecol,
              uint* __restrict__ qtbl, float* __restrict__ S_glob, int V) {
  __shared__ float S_part[128];
  int tid = threadIdx.x, wv = tid >> 6, l = tid & 63, c = l & 15, quad = l >> 4;
  if (tid < 128) S_part[tid] = 0.f;
  __syncthreads();

  int vb = blockIdx.x * 64 + wv * 16;
  int vrow = vb + c; if (vrow > V - 1) vrow = V - 1;

  #define DECLE(kt, ks) ui4v eb##kt##_##ks;
  REPB(DECLE)
  {
    #define LOADE(kt, ks) { \
      const uint2* t2_ = (const uint2*)(Ecol + (size_t)(16 * (kt) + c) * 64 + 16 * (ks) + 2 * quad); \
      uint2 lo_ = t2_[0], hi_ = t2_[4]; \
      eb##kt##_##ks.x = lo_.x; eb##kt##_##ks.y = lo_.y; \
      eb##kt##_##ks.z = hi_.x; eb##kt##_##ks.w = hi_.y; }
    REPB(LOADE)
    #define PINE(kt, ks) asm volatile("" : "+a"(eb##kt##_##ks));
    REPB(PINE)
  }

  const float4* vr = (const float4*)(vocab + (size_t)vrow * 128);
  ui4v va0, va1, va2, va3;
  #define MKVA(ks, dst) { \
    float4 a_ = vr[8 * (ks) + quad]; \
    float4 b_ = vr[8 * (ks) + 4 + quad]; \
    dst.x = cvtpk(a_.x, a_.y); dst.y = cvtpk(a_.z, a_.w); \
    dst.z = cvtpk(b_.x, b_.y); dst.w = cvtpk(b_.z, b_.w); }
  MKVA(0, va0) MKVA(1, va1) MKVA(2, va2) MKVA(3, va3)

  fx4 zz4; zz4.x = 0.f; zz4.y = 0.f; zz4.z = 0.f; zz4.w = 0.f;
  #define CCKT(kt) \
    fx4 cc##kt = MFMA(va0, eb##kt##_0, zz4); \
    cc##kt = MFMA(va1, eb##kt##_1, cc##kt); \
    cc##kt = MFMA(va2, eb##kt##_2, cc##kt); \
    cc##kt = MFMA(va3, eb##kt##_3, cc##kt);
  CCKT(0) CCKT(1) CCKT(2) CCKT(3) CCKT(4) CCKT(5) CCKT(6) CCKT(7)

  int v0 = vb + 4 * quad;
  #define ESUM(kt) { \
    float se_ = 0.f; \
    if (v0 + 0 < V) se_ += __expf(cc##kt.x); \
    if (v0 + 1 < V) se_ += __expf(cc##kt.y); \
    if (v0 + 2 < V) se_ += __expf(cc##kt.z); \
    if (v0 + 3 < V) se_ += __expf(cc##kt.w); \
    atomicAdd(&S_part[16 * (kt) + c], se_); }
  ESUM(0) ESUM(1) ESUM(2) ESUM(3) ESUM(4) ESUM(5) ESUM(6) ESUM(7)

  #define STKT(kt) { \
    float nx_ = __shfl_xor(cc##kt.x, 1, 64); \
    float ny_ = __shfl_xor(cc##kt.y, 1, 64); \
    float nz_ = __shfl_xor(cc##kt.z, 1, 64); \
    float nw_ = __shfl_xor(cc##kt.w, 1, 64); \
    if (!(c & 1)) { \
      int j_ = 8 * (kt) + (c >> 1); \
      if (v0 + 0 < V) qtbl[(size_t)(v0 + 0) * 64 + j_] = bfpack(cc##kt.x, nx_); \
      if (v0 + 1 < V) qtbl[(size_t)(v0 + 1) * 64 + j_] = bfpack(cc##kt.y, ny_); \
      if (v0 + 2 < V) qtbl[(size_t)(v0 + 2) * 64 + j_] = bfpack(cc##kt.z, nz_); \
      if (v0 + 3 < V) qtbl[(size_t)(v0 + 3) * 64 + j_] = bfpack(cc##kt.w, nw_); \
    } }
  STKT(0) STKT(1) STKT(2) STKT(3) STKT(4) STKT(5) STKT(6) STKT(7)

  __syncthreads();
  if (tid < 128) atomicAdd(&S_glob[tid], S_part[tid]);
}

// ---------- K2c: in-place q[v][k] = exp(emis - Emax_v) (bf16), Emax table ----------
__global__ __launch_bounds__(256) void k_qtab(uint* __restrict__ qtbl,
    const float* __restrict__ S_glob, float* __restrict__ Emax, int V) {
  int tid = threadIdx.x;
  int l = tid & 63;
  int v = blockIdx.x * 4 + (tid >> 6);
  if (v >= V) return;
  float2 S2 = ((const float2*)S_glob)[l];
  float z0 = __logf(S2.x), z1 = __logf(S2.y);
  size_t off = (size_t)v * 64 + l;
  uint d = qtbl[off];
  float e0 = bflo(d) - z0, e1 = bfhi(d) - z1;
  float m = fmaxf(e0, e1);
  #pragma unroll
  for (int s = 1; s < 64; s <<= 1) m = fmaxf(m, __shfl_xor(m, s, 64));
  float q0 = __expf(e0 - m), q1 = __expf(e1 - m);
  qtbl[off] = bfpack(q0, q1);
  if (l == 0) Emax[v] = m;
}

// =====================================================================
// PHASE 1 (S-form, register-resident, stage-pipelined): R9-exact, 515us.
// Frozen: MFMA pipe 51% busy (19.4cyc/MFMA/SIMD x 64/fold-pair), VALU
// ~17%, residual = per-wave dep stalls (insensitive to stage-pipelining,
// de-phasing, decorrelation); 2 waves/SIMD reg-capped (128V + 128A).
// =====================================================================
#define MST0(OUT, BN) \
  OUT##0 = MFMA(tb0_0, BN, zz4); OUT##1 = MFMA(tb1_0, BN, zz4); \
  OUT##2 = MFMA(tb2_0, BN, zz4); OUT##3 = MFMA(tb3_0, BN, zz4); \
  OUT##4 = MFMA(tb4_0, BN, zz4); OUT##5 = MFMA(tb5_0, BN, zz4); \
  OUT##6 = MFMA(tb6_0, BN, zz4); OUT##7 = MFMA(tb7_0, BN, zz4);
#define MSTA(OUT, BN, ks) \
  OUT##0 = MFMA(tb0_##ks, BN, OUT##0); OUT##1 = MFMA(tb1_##ks, BN, OUT##1); \
  OUT##2 = MFMA(tb2_##ks, BN, OUT##2); OUT##3 = MFMA(tb3_##ks, BN, OUT##3); \
  OUT##4 = MFMA(tb4_##ks, BN, OUT##4); OUT##5 = MFMA(tb5_##ks, BN, OUT##5); \
  OUT##6 = MFMA(tb6_##ks, BN, OUT##6); OUT##7 = MFMA(tb7_##ks, BN, OUT##7);

#define PKPAIR(CCA, CCB, QA, QB, DOUT) { \
  float f0 = bflo(QA.x) * rs, f1 = bfhi(QA.x) * rs; \
  float f2 = bflo(QA.y) * rs, f3 = bfhi(QA.y) * rs; \
  float s0 = CCA.x * f0, s1 = CCA.y * f1, s2 = CCA.z * f2, s3 = CCA.w * f3; \
  fm = fmaxf(fm, fmaxf(fmaxf(s0, s1), fmaxf(s2, s3))); \
  uint p0, p1, p2, p3; \
  asm("v_cvt_pk_bf16_f32 %0, %1, %2" : "=v"(p0) : "v"(s0), "v"(s1)); \
  asm("v_cvt_pk_bf16_f32 %0, %1, %2" : "=v"(p1) : "v"(s2), "v"(s3)); \
  float g0 = bflo(QB.x) * rs, g1 = bfhi(QB.x) * rs; \
  float g2 = bflo(QB.y) * rs, g3 = bfhi(QB.y) * rs; \
  float t0 = CCB.x * g0, t1 = CCB.y * g1, t2 = CCB.z * g2, t3 = CCB.w * g3; \
  fm = fmaxf(fm, fmaxf(fmaxf(t0, t1), fmaxf(t2, t3))); \
  asm("v_cvt_pk_bf16_f32 %0, %1, %2" : "=v"(p2) : "v"(t0), "v"(t1)); \
  asm("v_cvt_pk_bf16_f32 %0, %1, %2" : "=v"(p3) : "v"(t2), "v"(t3)); \
  DOUT.x = p0; DOUT.y = p1; DOUT.z = p2; DOUT.w = p3; }

#define PKPAIR_NR(CCA, CCB, QA, QB, DOUT) { \
  float s0 = CCA.x * bflo(QA.x), s1 = CCA.y * bfhi(QA.x); \
  float s2 = CCA.z * bflo(QA.y), s3 = CCA.w * bfhi(QA.y); \
  uint p0, p1, p2, p3; \
  asm("v_cvt_pk_bf16_f32 %0, %1, %2" : "=v"(p0) : "v"(s0), "v"(s1)); \
  asm("v_cvt_pk_bf16_f32 %0, %1, %2" : "=v"(p1) : "v"(s2), "v"(s3)); \
  float t0 = CCB.x * bflo(QB.x), t1 = CCB.y * bfhi(QB.x); \
  float t2 = CCB.z * bflo(QB.y), t3 = CCB.w * bfhi(QB.y); \
  asm("v_cvt_pk_bf16_f32 %0, %1, %2" : "=v"(p2) : "v"(t0), "v"(t1)); \
  asm("v_cvt_pk_bf16_f32 %0, %1, %2" : "=v"(p3) : "v"(t2), "v"(t3)); \
  DOUT.x = p0; DOUT.y = p1; DOUT.z = p2; DOUT.w = p3; }

#define QLD(dst, tk, i) dst = *(const uint2*)(qtbl + ((size_t)(tk) << 6) + 8 * (i) + 2 * quad);

#define QRELOAD(Q, TKREG, FBASE) \
  QLD(Q##0, TKREG, 0) QLD(Q##1, TKREG, 1) QLD(Q##2, TKREG, 2) QLD(Q##3, TKREG, 3) \
  QLD(Q##4, TKREG, 4) QLD(Q##5, TKREG, 5) QLD(Q##6, TKREG, 6) QLD(Q##7, TKREG, 7) \
  { int fi_ = (FBASE) + 4; if (fi_ > 511) fi_ = 511; TKREG = xseg[fi_]; }

#define SLOT_RS(CIN, COUT, Q, TKREG, FBASE) { \
  rs = 1.0f / fmA;  llacc += __log2f(fmA); \
  float fm = 0.f; \
  PKPAIR(CIN##0, CIN##1, Q##0, Q##1, Bs0) \
  MST0(COUT, Bs0) \
  PKPAIR(CIN##2, CIN##3, Q##2, Q##3, Bs1) \
  MSTA(COUT, Bs1, 1) \
  PKPAIR(CIN##4, CIN##5, Q##4, Q##5, Bs2) \
  MSTA(COUT, Bs2, 2) \
  PKPAIR(CIN##6, CIN##7, Q##6, Q##7, Bs3) \
  MSTA(COUT, Bs3, 3) \
  QRELOAD(Q, TKREG, FBASE) \
  fm = fmaxf(fm, __shfl_xor(fm, 16, 64)); \
  fm = fmaxf(fm, __shfl_xor(fm, 32, 64)); \
  fmA = fmaxf(fm, 1e-33f); \
}

#define SLOT_NR(CIN, COUT, Q, TKREG, FBASE) { \
  PKPAIR_NR(CIN##0, CIN##1, Q##0, Q##1, Bs0) \
  MST0(COUT, Bs0) \
  PKPAIR_NR(CIN##2, CIN##3, Q##2, Q##3, Bs1) \
  MSTA(COUT, Bs1, 1) \
  PKPAIR_NR(CIN##4, CIN##5, Q##4, Q##5, Bs2) \
  MSTA(COUT, Bs2, 2) \
  PKPAIR_NR(CIN##6, CIN##7, Q##6, Q##7, Bs3) \
  MSTA(COUT, Bs3, 3) \
  QRELOAD(Q, TKREG, FBASE) \
}

__global__ __attribute__((amdgpu_flat_work_group_size(512, 512), amdgpu_waves_per_eu(2)))
void k_seg(const int* __restrict__ x, const uint* __restrict__ Tcol,
           const uint* __restrict__ qtbl, uint* __restrict__ Pst,
           float* __restrict__ LLseg) {
  int tid = threadIdx.x;
  int wv = tid >> 6, l = tid & 63, c = l & 15, quad = l >> 4;
  int blk = blockIdx.x;
  const int* xseg = x + (size_t)(blk >> 3) * 4096 + (size_t)(blk & 7) * 512;

  #define DECLB(nt, ks) ui4v tb##nt##_##ks;
  REPB(DECLB)
  {
    #define LOADB(nt, ks) { \
      const uint2* t2_ = (const uint2*)(Tcol + (size_t)(16 * (nt) + c) * 64 + 16 * (ks) + 2 * quad); \
      uint2 lo_ = t2_[0], hi_ = t2_[4]; \
      tb##nt##_##ks.x = lo_.x; tb##nt##_##ks.y = lo_.y; \
      tb##nt##_##ks.z = hi_.x; tb##nt##_##ks.w = hi_.y; }
    REPB(LOADB)
    #define PINB(nt, ks) asm volatile("" : "+a"(tb##nt##_##ks));
    REPB(PINB)
  }

  ui4v Bs0, Bs1, Bs2, Bs3;
  {
    uint iv = (quad == (c >> 2)) ? (0x3F80u << (16 * (c & 1))) : 0u;
    int dsel = ((c >> 1) & 1) + 2 * (wv & 1);
    int kssel = wv >> 1;
    Bs0.x = (kssel == 0 && dsel == 0) ? iv : 0u;
    Bs0.y = (kssel == 0 && dsel == 1) ? iv : 0u;
    Bs0.z = (kssel == 0 && dsel == 2) ? iv : 0u;
    Bs0.w = (kssel == 0 && dsel == 3) ? iv : 0u;
    Bs1.x = (kssel == 1 && dsel == 0) ? iv : 0u;
    Bs1.y = (kssel == 1 && dsel == 1) ? iv : 0u;
    Bs1.z = (kssel == 1 && dsel == 2) ? iv : 0u;
    Bs1.w = (kssel == 1 && dsel == 3) ? iv : 0u;
    Bs2.x = (kssel == 2 && dsel == 0) ? iv : 0u;
    Bs2.y = (kssel == 2 && dsel == 1) ? iv : 0u;
    Bs2.z = (kssel == 2 && dsel == 2) ? iv : 0u;
    Bs2.w = (kssel == 2 && dsel == 3) ? iv : 0u;
    Bs3.x = (kssel == 3 && dsel == 0) ? iv : 0u;
    Bs3.y = (kssel == 3 && dsel == 1) ? iv : 0u;
    Bs3.z = (kssel == 3 && dsel == 2) ? iv : 0u;
    Bs3.w = (kssel == 3 && dsel == 3) ? iv : 0u;
  }

  float rs = 1.0f, llacc = 0.0f, fmA = 1.0f;
  fx4 zz4; zz4.x = 0.f; zz4.y = 0.f; zz4.z = 0.f; zz4.w = 0.f;

  fx4 cA0, cA1, cA2, cA3, cA4, cA5, cA6, cA7;
  fx4 cB0, cB1, cB2, cB3, cB4, cB5, cB6, cB7;

  int tk0 = xseg[0], tk1 = xseg[1];
  int tkA = xseg[2], tkB = xseg[3];
  uint2 qc0, qc1, qc2, qc3, qc4, qc5, qc6, qc7;
  uint2 qn0, qn1, qn2, qn3, qn4, qn5, qn6, qn7;
  QLD(qc0, tk0, 0) QLD(qc1, tk0, 1) QLD(qc2, tk0, 2) QLD(qc3, tk0, 3)
  QLD(qc4, tk0, 4) QLD(qc5, tk0, 5) QLD(qc6, tk0, 6) QLD(qc7, tk0, 7)
  QLD(qn0, tk1, 0) QLD(qn1, tk1, 1) QLD(qn2, tk1, 2) QLD(qn3, tk1, 3)
  QLD(qn4, tk1, 4) QLD(qn5, tk1, 5) QLD(qn6, tk1, 6) QLD(qn7, tk1, 7)

  MST0(cA, Bs0) MSTA(cA, Bs1, 1) MSTA(cA, Bs2, 2) MSTA(cA, Bs3, 3)

  if (wv & 1) __builtin_amdgcn_s_sleep(8);

  for (int f4 = 0; f4 < 128; ++f4) {
    int f = f4 * 4;
    SLOT_RS(cA, cB, qc, tkA, f)
    SLOT_NR(cB, cA, qn, tkB, f + 1)
    SLOT_NR(cA, cB, qc, tkA, f + 2)
    SLOT_NR(cB, cA, qn, tkB, f + 3)
  }

  size_t pb = (size_t)blk * 8192 + (size_t)(16 * wv + c) * 64;
  uint2 st;
  st.x = Bs0.x; st.y = Bs0.y; *(uint2*)(Pst + pb +  0 + 2 * quad) = st;
  st.x = Bs0.z; st.y = Bs0.w; *(uint2*)(Pst + pb +  8 + 2 * quad) = st;
  st.x = Bs1.x; st.y = Bs1.y; *(uint2*)(Pst + pb + 16 + 2 * quad) = st;
  st.x = Bs1.z; st.y = Bs1.w; *(uint2*)(Pst + pb + 24 + 2 * quad) = st;
  st.x = Bs2.x; st.y = Bs2.y; *(uint2*)(Pst + pb + 32 + 2 * quad) = st;
  st.x = Bs2.z; st.y = Bs2.w; *(uint2*)(Pst + pb + 40 + 2 * quad) = st;
  st.x = Bs3.x; st.y = Bs3.y; *(uint2*)(Pst + pb + 48 + 2 * quad) = st;
  st.x = Bs3.z; st.y = Bs3.w; *(uint2*)(Pst + pb + 56 + 2 * quad) = st;
  if (quad == 0)
    LLseg[(size_t)blk * 128 + 16 * wv + c] = llacc * 0.6931471805599453f;
}

// =====================================================================
// PHASE 2 (8-wave, absorbs Emax token-sum): per chain, alpha0 -> fold 8
// segment matrices.  Row-dim of each 128x128 matvec split across 8
// waves (2 u4-entries each -> 16-load chains); partials LDS-reduced by
// wave 0.  Per-chain sum of Emax[x[t]] gathered up-front (8/thread) and
// added to the chain LL (replaces the k_emaxsum kernel).
// =====================================================================
__global__ __launch_bounds__(512, 1) void k_comb(
    const float* __restrict__ start_w, const float* __restrict__ start_b,
    const uint* __restrict__ Pst, const float* __restrict__ LLseg,
    const int* __restrict__ x, const float* __restrict__ Emax,
    float* __restrict__ chainLL) {
  __shared__ uint al[64] __attribute__((aligned(16)));
  __shared__ float2 part[8][64];
  __shared__ float esum[8];
  int n = blockIdx.x, tid = threadIdx.x;
  int wv = tid >> 6, l = tid & 63;
  const int* xrow = x + (size_t)n * 4096;

  // per-chain Emax token-sum (all 8 waves)
  float es = 0.f;
  #pragma unroll
  for (int t = 0; t < 8; ++t) es += Emax[xrow[tid + 512 * t]];
  #pragma unroll
  for (int mk = 1; mk < 64; mk <<= 1) es += __shfl_xor(es, mk, 64);
  if (l == 0) esum[wv] = es;

  float p0 = 0.f, p1 = 0.f, LLacc = 0.f;
  if (wv == 0) {
    float a0i = start_w[2 * l] + start_b[2 * l];
    float a1i = start_w[2 * l + 1] + start_b[2 * l + 1];
    float m = fmaxf(a0i, a1i);
    #pragma unroll
    for (int s = 1; s < 64; s <<= 1) m = fmaxf(m, __shfl_xor(m, s, 64));
    p0 = __expf(a0i - m); p1 = __expf(a1i - m);
    float tot = p0 + p1;
    #pragma unroll
    for (int s = 1; s < 64; s <<= 1) tot += __shfl_xor(tot, s, 64);
    LLacc = m + __logf(tot);
    float inv = 1.0f / tot;
    p0 *= inv; p1 *= inv;
  }
  const uint4_a* u4 = (const uint4_a*)al;

  for (int s = 0; s < 8; ++s) {
    float g = 0.f;
    if (wv == 0) {
      float La = LLseg[(size_t)(n * 8 + s) * 128 + 2 * l];
      float Lb = LLseg[(size_t)(n * 8 + s) * 128 + 2 * l + 1];
      g = fmaxf(La, Lb);
      #pragma unroll
      for (int sh = 1; sh < 64; sh <<= 1) g = fmaxf(g, __shfl_xor(g, sh, 64));
      al[l] = bfpack(p0 * __expf(La - g), p1 * __expf(Lb - g));
    }
    __syncthreads();

    const uint* pb = Pst + (size_t)(n * 8 + s) * 8192;
    float o0 = 0.f, o1 = 0.f;
    #pragma unroll
    for (int ii = 0; ii < 2; ++ii) {
      int i = 2 * wv + ii;
      uint4 uu = u4[i];
      #pragma unroll
      for (int d = 0; d < 4; ++d) {
        uint ad = (d == 0) ? uu.x : (d == 1) ? uu.y : (d == 2) ? uu.z : uu.w;
        uint P0 = pb[(8 * i + 2 * d) * 64 + l];
        uint P1 = pb[(8 * i + 2 * d + 1) * 64 + l];
        float alo = bflo(ad), ahi = bfhi(ad);
        o0 = fmaf(alo, bflo(P0), o0); o0 = fmaf(ahi, bflo(P1), o0);
        o1 = fmaf(alo, bfhi(P0), o1); o1 = fmaf(ahi, bfhi(P1), o1);
      }
    }
    part[wv][l] = make_float2(o0, o1);
    __syncthreads();

    if (wv == 0) {
      float2 x0 = part[0][l], x1 = part[1][l], x2 = part[2][l], x3 = part[3][l];
      float2 x4 = part[4][l], x5 = part[5][l], x6 = part[6][l], x7 = part[7][l];
      float s0 = ((x0.x + x1.x) + (x2.x + x3.x)) + ((x4.x + x5.x) + (x6.x + x7.x));
      float s1 = ((x0.y + x1.y) + (x2.y + x3.y)) + ((x4.y + x5.y) + (x6.y + x7.y));
      float tt = s0 + s1;
      #pragma unroll
      for (int sh = 1; sh < 64; sh <<= 1) tt += __shfl_xor(tt, sh, 64);
      LLacc += g + __logf(tt);
      float it = 1.0f / tt;
      p0 = s0 * it; p1 = s1 * it;
    }
  }
  if (tid == 0) {
    float et = ((esum[0] + esum[1]) + (esum[2] + esum[3])) +
               ((esum[4] + esum[5]) + (esum[6] + esum[7]));
    chainLL[n] = LLacc + et;
  }
}

// =====================================================================
// FALLBACK: sequential scan, 4 waves per chain — used if ws too small
// =====================================================================
#define RLU(i) ((uint)__builtin_amdgcn_readlane((int)ud, rbase + (i)))
#if HAVE_BFDOT
#define DOTS \
  uint u0=RLU(0),u1=RLU(1),u2=RLU(2),u3=RLU(3),u4=RLU(4),u5=RLU(5),u6=RLU(6),u7=RLU(7), \
       u8=RLU(8),u9=RLU(9),u10=RLU(10),u11=RLU(11),u12=RLU(12),u13=RLU(13),u14=RLU(14),u15=RLU(15); \
  float A0 = dot2bf(u0, tA0.x, 0.f), A1 = dot2bf(u1, tA0.y, 0.f); \
  float A2 = dot2bf(u2, tA0.z, 0.f), A3 = dot2bf(u3, tA0.w, 0.f); \
  float B0 = dot2bf(u0, tB0.x, 0.f), B1 = dot2bf(u1, tB0.y, 0.f); \
  float B2 = dot2bf(u2, tB0.z, 0.f), B3 = dot2bf(u3, tB0.w, 0.f); \
  A0 = dot2bf(u4, tA1.x, A0); A1 = dot2bf(u5, tA1.y, A1); \
  A2 = dot2bf(u6, tA1.z, A2); A3 = dot2bf(u7, tA1.w, A3); \
  B0 = dot2bf(u4, tB1.x, B0); B1 = dot2bf(u5, tB1.y, B1); \
  B2 = dot2bf(u6, tB1.z, B2); B3 = dot2bf(u7, tB1.w, B3); \
  A0 = dot2bf(u8, tA2.x, A0); A1 = dot2bf(u9, tA2.y, A1); \
  A2 = dot2bf(u10, tA2.z, A2); A3 = dot2bf(u11, tA2.w, A3); \
  B0 = dot2bf(u8, tB2.x, B0); B1 = dot2bf(u9, tB2.y, B1); \
  B2 = dot2bf(u10, tB2.z, B2); B3 = dot2bf(u11, tB2.w, B3); \
  A0 = dot2bf(u12, tA3.x, A0); A1 = dot2bf(u13, tA3.y, A1); \
  A2 = dot2bf(u14, tA3.z, A2); A3 = dot2bf(u15, tA3.w, A3); \
  B0 = dot2bf(u12, tB3.x, B0); B1 = dot2bf(u13, tB3.y, B1); \
  B2 = dot2bf(u14, tB3.z, B2); B3 = dot2bf(u15, tB3.w, B3); \
  float Asum = (A0 + A1) + (A2 + A3), Bsum = (B0 + B1) + (B2 + B3);
#else
#define ACC2(i, AA, BB) { uint tu = RLU(i); float lo = bflo(tu), hi = bfhi(tu); \
  AA += lo * fa##i.x; AA += hi * fa##i.y; BB += lo * fb##i.x; BB += hi * fb##i.y; }
#define DOTS \
  float A0 = 0.f, A1 = 0.f, A2 = 0.f, A3 = 0.f; \
  float B0 = 0.f, B1 = 0.f, B2 = 0.f, B3 = 0.f; \
  ACC2(0, A0, B0) ACC2(1, A1, B1) ACC2(2, A2, B2) ACC2(3, A3, B3) \
  ACC2(4, A0, B0) ACC2(5, A1, B1) ACC2(6, A2, B2) ACC2(7, A3, B3) \
  ACC2(8, A0, B0) ACC2(9, A1, B1) ACC2(10, A2, B2) ACC2(11, A3, B3) \
  ACC2(12, A0, B0) ACC2(13, A1, B1) ACC2(14, A2, B2) ACC2(15, A3, B3) \
  float Asum = (A0 + A1) + (A2 + A3), Bsum = (B0 + B1) + (B2 + B3);
#endif

#define STEPF(j, p) { \
  DOTS \
  *(float2*)&partLDS[(p) * 640 + l * 10 + 2 * wv] = make_float2(Asum, Bsum); \
  asm volatile("s_waitcnt lgkmcnt(0)\ns_barrier" ::: "memory"); \
  const float2* pr = (const float2*)&partLDS[(p) * 640 + l * 10]; \
  float2 x0 = pr[0], x1 = pr[1], x2 = pr[2], x3 = pr[3]; \
  float s0 = (x0.x + x1.x) + (x2.x + x3.x); \
  float s1 = (x0.y + x1.y) + (x2.y + x3.y); \
  float nu0 = s0 * bflo(qc##j), nu1 = s1 * bfhi(qc##j); \
  qc##j = qtbl[(size_t)tk##j * 64 + l]; \
  tk##j = xrow[(tbase + (j) + 16) & 4095]; \
  if ((j) == 7) { \
    float tt = nu0 + nu1; \
    for (int s = 1; s < 64; s <<= 1) tt += __shfl_xor(tt, s, 64); \
    LLacc += __logf(tt); \
    float it = 1.0f / tt; nu0 *= it; nu1 *= it; \
  } \
  ud = bfpack(nu0, nu1); }

__global__ __launch_bounds__(256, 1) void k_chain(const int* __restrict__ x,
    const float* __restrict__ start_w, const float* __restrict__ start_b,
    const uint* __restrict__ Tcol, const uint* __restrict__ qtbl,
    float* __restrict__ chainLL) {
  __shared__ float partLDS[1280];
  int n = blockIdx.x;
  int l = threadIdx.x & 63;
  int wv = __builtin_amdgcn_readfirstlane((int)(threadIdx.x >> 6));
  int rbase = wv * 16;
  const int* xrow = x + (size_t)n * 4096;

  const uint4* ca = (const uint4*)(Tcol + (2 * l) * 64 + rbase);
  const uint4* cb = (const uint4*)(Tcol + (2 * l + 1) * 64 + rbase);
  uint4 tA0 = ca[0], tA1 = ca[1], tA2 = ca[2], tA3 = ca[3];
  uint4 tB0 = cb[0], tB1 = cb[1], tB2 = cb[2], tB3 = cb[3];
#if !HAVE_BFDOT
  float2 fa0 = make_float2(bflo(tA0.x), bfhi(tA0.x)), fa1 = make_float2(bflo(tA0.y), bfhi(tA0.y));
  float2 fa2 = make_float2(bflo(tA0.z), bfhi(tA0.z)), fa3 = make_float2(bflo(tA0.w), bfhi(tA0.w));
  float2 fa4 = make_float2(bflo(tA1.x), bfhi(tA1.x)), fa5 = make_float2(bflo(tA1.y), bfhi(tA1.y));
  float2 fa6 = make_float2(bflo(tA1.z), bfhi(tA1.z)), fa7 = make_float2(bflo(tA1.w), bfhi(tA1.w));
  float2 fa8 = make_float2(bflo(tA2.x), bfhi(tA2.x)), fa9 = make_float2(bflo(tA2.y), bfhi(tA2.y));
  float2 fa10 = make_float2(bflo(tA2.z), bfhi(tA2.z)), fa11 = make_float2(bflo(tA2.w), bfhi(tA2.w));
  float2 fa12 = make_float2(bflo(tA3.x), bfhi(tA3.x)), fa13 = make_float2(bflo(tA3.y), bfhi(tA3.y));
  float2 fa14 = make_float2(bflo(tA3.z), bfhi(tA3.z)), fa15 = make_float2(bflo(tA3.w), bfhi(tA3.w));
  float2 fb0 = make_float2(bflo(tB0.x), bfhi(tB0.x)), fb1 = make_float2(bflo(tB0.y), bfhi(tB0.y));
  float2 fb2 = make_float2(bflo(tB0.z), bfhi(tB0.z)), fb3 = make_float2(bflo(tB0.w), bfhi(tB0.w));
  float2 fb4 = make_float2(bflo(tB1.x), bfhi(tB1.x)), fb5 = make_float2(bflo(tB1.y), bfhi(tB1.y));
  float2 fb6 = make_float2(bflo(tB1.z), bfhi(tB1.z)), fb7 = make_float2(bflo(tB1.w), bfhi(tB1.w));
  float2 fb8 = make_float2(bflo(tB2.x), bfhi(tB2.x)), fb9 = make_float2(bflo(tB2.y), bfhi(tB2.y));
  float2 fb10 = make_float2(bflo(tB2.z), bfhi(tB2.z)), fb11 = make_float2(bflo(tB2.w), bfhi(tB2.w));
  float2 fb12 = make_float2(bflo(tB3.x), bfhi(tB3.x)), fb13 = make_float2(bflo(tB3.y), bfhi(tB3.y));
  float2 fb14 = make_float2(bflo(tB3.z), bfhi(tB3.z)), fb15 = make_float2(bflo(tB3.w), bfhi(tB3.w));
#endif

  float a0i = start_w[2 * l] + start_b[2 * l];
  float a1i = start_w[2 * l + 1] + start_b[2 * l + 1];
  float m = fmaxf(a0i, a1i);
  #pragma unroll
  for (int s = 1; s < 64; s <<= 1) m = fmaxf(m, __shfl_xor(m, s, 64));
  float p0 = __expf(a0i - m), p1 = __expf(a1i - m);
  float tot = p0 + p1;
  #pragma unroll
  for (int s = 1; s < 64; s <<= 1) tot += __shfl_xor(tot, s, 64);
  float LLacc = m + __logf(tot);
  float inv = 1.0f / tot;
  uint ud = bfpack(p0 * inv, p1 * inv);

  uint qc0 = qtbl[(size_t)xrow[0] * 64 + l], qc1 = qtbl[(size_t)xrow[1] * 64 + l];
  uint qc2 = qtbl[(size_t)xrow[2] * 64 + l], qc3 = qtbl[(size_t)xrow[3] * 64 + l];
  uint qc4 = qtbl[(size_t)xrow[4] * 64 + l], qc5 = qtbl[(size_t)xrow[5] * 64 + l];
  uint qc6 = qtbl[(size_t)xrow[6] * 64 + l], qc7 = qtbl[(size_t)xrow[7] * 64 + l];
  int tk0 = xrow[8],  tk1 = xrow[9],  tk2 = xrow[10], tk3 = xrow[11];
  int tk4 = xrow[12], tk5 = xrow[13], tk6 = xrow[14], tk7 = xrow[15];

  for (int t8 = 0; t8 < 512; ++t8) {
    int tbase = t8 * 8;
    STEPF(0, 0) STEPF(1, 1) STEPF(2, 0) STEPF(3, 1)
    STEPF(4, 0) STEPF(5, 1) STEPF(6, 0) STEPF(7, 1)
  }
  if (l == 0 && wv == 0) chainLL[n] = LLacc;
}

// ---------- K4a: sum of Emax over all tokens (fallback path only) ----------
__global__ __launch_bounds__(256) void k_emaxsum(const int* __restrict__ x,
    const float* __restrict__ Emax, float* __restrict__ sumE, int NT) {
  int idx = blockIdx.x * 256 + threadIdx.x;
  float s = 0.f;
  for (; idx < NT; idx += 128 * 256) s += Emax[x[idx]];
  #pragma unroll
  for (int mk = 1; mk < 64; mk <<= 1) s += __shfl_xor(s, mk, 64);
  if ((threadIdx.x & 63) == 0) atomicAdd(sumE, s);
}

// ---------- K4b: final scalar (sumE = 0 on main path) ----------
__global__ void k_final(const float* __restrict__ chainLL, const float* __restrict__ sumE,
                        float* __restrict__ out, int N) {
  int l = threadIdx.x;
  float v = (l < N) ? chainLL[l] : 0.f;
  #pragma unroll
  for (int mk = 1; mk < 64; mk <<= 1) v += __shfl_xor(v, mk, 64);
  if (l == 0) out[0] = -(v + sumE[0]) / (float)N;
}

extern "C" void kernel_launch(void* const* d_in, const int* in_sizes, int n_in,
                              void* d_out, int out_size, void* d_ws, size_t ws_size,
                              hipStream_t stream) {
  if (n_in < 6) return;
  const int*   x       = (const int*)d_in[0];
  const float* start_w = (const float*)d_in[1];
  const float* start_b = (const float*)d_in[2];
  const float* trans_w = (const float*)d_in[3];
  const float* emb_w   = (const float*)d_in[4];
  const float* vocab_w = (const float*)d_in[5];
  int NT = in_sizes[0];
  int N  = NT / 4096;
  int V  = in_sizes[5] / 128;

  char* ws = (char*)d_ws;
  float* S_glob  = (float*)(ws + 0);        // 128 f
  float* sumE    = (float*)(ws + 512);      // 1 f (stays 0 on main path)
  float* chainLL = (float*)(ws + 768);      // N f
  uint*  Tcol    = (uint*)(ws + 1024);      // 32 KB (ends 33792)
  uint*  Ecol    = (uint*)(ws + 36864);     // 32 KB (ends 69632)
  float* Emax    = (float*)(ws + 73728);    // V floats
  size_t qtbl_off = 73728 + (size_t)V * 4;
  qtbl_off = (qtbl_off + 255) & ~(size_t)255;
  uint*  qtbl    = (uint*)(ws + qtbl_off);  // V*64 dwords
  size_t pst_off = qtbl_off + (size_t)V * 256;
  uint*  Pst     = (uint*)(ws + pst_off);   // N*8*8192 dwords
  size_t llseg_off = pst_off + (size_t)N * 8 * 8192 * 4;
  float* LLseg   = (float*)(ws + llseg_off);  // N*8*128 floats
  size_t need    = llseg_off + (size_t)N * 8 * 128 * 4 + 64;

  hipMemsetAsync(d_ws, 0, 1024, stream);
  k_prep<<<dim3(128), dim3(128), 0, stream>>>(trans_w, emb_w, Tcol, Ecol);
  k_logits<<<dim3((V + 63) / 64), dim3(256), 0, stream>>>(vocab_w, Ecol, qtbl, S_glob, V);
  k_qtab<<<dim3((V + 3) / 4), dim3(256), 0, stream>>>(qtbl, S_glob, Emax, V);
  if (ws_size >= need) {
    k_seg<<<dim3(N * 8), dim3(512), 0, stream>>>(x, Tcol, qtbl, Pst, LLseg);
    k_comb<<<dim3(N), dim3(512), 0, stream>>>(start_w, start_b, Pst, LLseg, x, Emax, chainLL);
  } else {
    k_chain<<<dim3(N), dim3(256), 0, stream>>>(x, start_w, start_b, Tcol, qtbl, chainLL);
    k_emaxsum<<<dim3(128), dim3(256), 0, stream>>>(x, Emax, sumE, NT);
  }
  k_final<<<dim3(1), dim3(64), 0, stream>>>(chainLL, sumE, (float*)d_out, N);
}

// Round 14
// 591.749 us; speedup vs baseline: 1.2574x; 1.0208x over previous
//
#include <hip/hip_runtime.h>

typedef unsigned int uint;
typedef unsigned short ushort;
typedef uint4 uint4_a __attribute__((may_alias));
typedef uint ui4v __attribute__((ext_vector_type(4)));
typedef float fx4 __attribute__((ext_vector_type(4)));
typedef short s8v __attribute__((ext_vector_type(8)));

// ---------- bf16 helpers ----------
__device__ __forceinline__ uint bfpack(float a, float b) {
  uint ua = __float_as_uint(a), ub = __float_as_uint(b);
  ua += 0x7fffu + ((ua >> 16) & 1u);   // RNE
  ub += 0x7fffu + ((ub >> 16) & 1u);
  return (ua >> 16) | (ub & 0xffff0000u);
}
__device__ __forceinline__ float bflo(uint d) { return __uint_as_float(d << 16); }
__device__ __forceinline__ float bfhi(uint d) { return __uint_as_float(d & 0xffff0000u); }
__device__ __forceinline__ ushort bfr(float s) {
  return (ushort)((__float_as_uint(s) + 0x8000u) >> 16);
}
__device__ __forceinline__ uint cvtpk(float a, float b) {
  uint r; asm("v_cvt_pk_bf16_f32 %0, %1, %2" : "=v"(r) : "v"(a), "v"(b)); return r;
}

#if __has_builtin(__builtin_amdgcn_fdot2_f32_bf16)
#define HAVE_BFDOT 1
typedef __bf16 v2bf __attribute__((ext_vector_type(2)));
__device__ __forceinline__ float dot2bf(uint a, uint b, float c) {
  return __builtin_amdgcn_fdot2_f32_bf16(__builtin_bit_cast(v2bf, a),
                                         __builtin_bit_cast(v2bf, b), c, false);
}
#else
#define HAVE_BFDOT 0
#endif

// ---------- shared MFMA helpers (fragment conventions verified by k_seg) ----------
#define REPB(M) M(0,0) M(0,1) M(0,2) M(0,3) M(1,0) M(1,1) M(1,2) M(1,3) \
                M(2,0) M(2,1) M(2,2) M(2,3) M(3,0) M(3,1) M(3,2) M(3,3) \
                M(4,0) M(4,1) M(4,2) M(4,3) M(5,0) M(5,1) M(5,2) M(5,3) \
                M(6,0) M(6,1) M(6,2) M(6,3) M(7,0) M(7,1) M(7,2) M(7,3)

#define MFMA(a, b, c) __builtin_amdgcn_mfma_f32_16x16x32_bf16( \
    __builtin_bit_cast(s8v, a), __builtin_bit_cast(s8v, b), c, 0, 0, 0)

// ---------- K1 (merged): blocks <64 -> Tcol column pairs; >=64 -> Ecol pack ----------
__global__ __launch_bounds__(128) void k_prep(const float* __restrict__ w,
                                              const float* __restrict__ emb,
                                              uint* __restrict__ Tcol,
                                              uint* __restrict__ Ecol) {
  int blk = blockIdx.x, tid = threadIdx.x;
  if (blk < 64) {
    __shared__ float rowLSE[128];
    const float4* w4 = (const float4*)(w + tid * 128);
    float se = 0.f;
    #pragma unroll 8
    for (int i = 0; i < 32; ++i) {
      float4 v = w4[i];
      se += __expf(v.x) + __expf(v.y) + __expf(v.z) + __expf(v.w);
    }
    rowLSE[tid] = __logf(se);
    __syncthreads();
    int j = tid & 63;
    int c = 2 * blk + (tid >> 6);
    float a = __expf(w[(2 * j) * 128 + c]     - rowLSE[2 * j]);
    float b = __expf(w[(2 * j + 1) * 128 + c] - rowLSE[2 * j + 1]);
    Tcol[c * 64 + j] = bfpack(a, b);
  } else {
    int t = (blk - 64) * 128 + tid;          // 64 blocks x 128 = 8192
    float2 e = *(const float2*)(emb + 2 * t);
    Ecol[t] = bfpack(e.x, e.y);
  }
}

// ---------- K2a (MFMA): logits + per-k exp sums; 256 vocab rows/block ----------
// Ecol AGPR table loaded ONCE per block and reused across 4 x 64-row groups.
__global__ __attribute__((amdgpu_flat_work_group_size(256, 256)))
void k_logits(const float* __restrict__ vocab, const uint* __restrict__ Ecol,
              uint* __restrict__ qtbl, float* __restrict__ S_glob, int V) {
  __shared__ float S_part[128];
  int tid = threadIdx.x, wv = tid >> 6, l = tid & 63, c = l & 15, quad = l >> 4;
  if (tid < 128) S_part[tid] = 0.f;
  __syncthreads();

  #define DECLE(kt, ks) ui4v eb##kt##_##ks;
  REPB(DECLE)
  {
    #define LOADE(kt, ks) { \
      const uint2* t2_ = (const uint2*)(Ecol + (size_t)(16 * (kt) + c) * 64 + 16 * (ks) + 2 * quad); \
      uint2 lo_ = t2_[0], hi_ = t2_[4]; \
      eb##kt##_##ks.x = lo_.x; eb##kt##_##ks.y = lo_.y; \
      eb##kt##_##ks.z = hi_.x; eb##kt##_##ks.w = hi_.y; }
    REPB(LOADE)
    #define PINE(kt, ks) asm volatile("" : "+a"(eb##kt##_##ks));
    REPB(PINE)
  }

  fx4 zz4; zz4.x = 0.f; zz4.y = 0.f; zz4.z = 0.f; zz4.w = 0.f;

  for (int it = 0; it < 4; ++it) {
    int vb = blockIdx.x * 256 + it * 64 + wv * 16;
    int vrow = vb + c; if (vrow > V - 1) vrow = V - 1;
    const float4* vr = (const float4*)(vocab + (size_t)vrow * 128);
    ui4v va0, va1, va2, va3;
    #define MKVA(ks, dst) { \
      float4 a_ = vr[8 * (ks) + quad]; \
      float4 b_ = vr[8 * (ks) + 4 + quad]; \
      dst.x = cvtpk(a_.x, a_.y); dst.y = cvtpk(a_.z, a_.w); \
      dst.z = cvtpk(b_.x, b_.y); dst.w = cvtpk(b_.z, b_.w); }
    MKVA(0, va0) MKVA(1, va1) MKVA(2, va2) MKVA(3, va3)

    #define CCKT(kt) \
      fx4 cc##kt = MFMA(va0, eb##kt##_0, zz4); \
      cc##kt = MFMA(va1, eb##kt##_1, cc##kt); \
      cc##kt = MFMA(va2, eb##kt##_2, cc##kt); \
      cc##kt = MFMA(va3, eb##kt##_3, cc##kt);
    CCKT(0) CCKT(1) CCKT(2) CCKT(3) CCKT(4) CCKT(5) CCKT(6) CCKT(7)

    int v0 = vb + 4 * quad;
    #define ESUM(kt) { \
      float se_ = 0.f; \
      if (v0 + 0 < V) se_ += __expf(cc##kt.x); \
      if (v0 + 1 < V) se_ += __expf(cc##kt.y); \
      if (v0 + 2 < V) se_ += __expf(cc##kt.z); \
      if (v0 + 3 < V) se_ += __expf(cc##kt.w); \
      atomicAdd(&S_part[16 * (kt) + c], se_); }
    ESUM(0) ESUM(1) ESUM(2) ESUM(3) ESUM(4) ESUM(5) ESUM(6) ESUM(7)

    #define STKT(kt) { \
      float nx_ = __shfl_xor(cc##kt.x, 1, 64); \
      float ny_ = __shfl_xor(cc##kt.y, 1, 64); \
      float nz_ = __shfl_xor(cc##kt.z, 1, 64); \
      float nw_ = __shfl_xor(cc##kt.w, 1, 64); \
      if (!(c & 1)) { \
        int j_ = 8 * (kt) + (c >> 1); \
        if (v0 + 0 < V) qtbl[(size_t)(v0 + 0) * 64 + j_] = bfpack(cc##kt.x, nx_); \
        if (v0 + 1 < V) qtbl[(size_t)(v0 + 1) * 64 + j_] = bfpack(cc##kt.y, ny_); \
        if (v0 + 2 < V) qtbl[(size_t)(v0 + 2) * 64 + j_] = bfpack(cc##kt.z, nz_); \
        if (v0 + 3 < V) qtbl[(size_t)(v0 + 3) * 64 + j_] = bfpack(cc##kt.w, nw_); \
      } }
    STKT(0) STKT(1) STKT(2) STKT(3) STKT(4) STKT(5) STKT(6) STKT(7)
  }

  __syncthreads();
  if (tid < 128) atomicAdd(&S_glob[tid], S_part[tid]);
}

// ---------- K2c: q[v][k] = exp(emis - Emax_v) (bf16); 16 rows/block ----------
__global__ __launch_bounds__(256) void k_qtab(uint* __restrict__ qtbl,
    const float* __restrict__ S_glob, float* __restrict__ Emax, int V) {
  int tid = threadIdx.x;
  int l = tid & 63;
  float2 S2 = ((const float2*)S_glob)[l];
  float z0 = __logf(S2.x), z1 = __logf(S2.y);
  #pragma unroll
  for (int it = 0; it < 4; ++it) {
    int v = blockIdx.x * 16 + it * 4 + (tid >> 6);
    if (v >= V) continue;
    size_t off = (size_t)v * 64 + l;
    uint d = qtbl[off];
    float e0 = bflo(d) - z0, e1 = bfhi(d) - z1;
    float m = fmaxf(e0, e1);
    #pragma unroll
    for (int s = 1; s < 64; s <<= 1) m = fmaxf(m, __shfl_xor(m, s, 64));
    float q0 = __expf(e0 - m), q1 = __expf(e1 - m);
    qtbl[off] = bfpack(q0, q1);
    if (l == 0) Emax[v] = m;
  }
}

// =====================================================================
// PHASE 1 (S-form, register-resident, stage-pipelined): R9-exact, ~520us.
// Frozen: MFMA pipe 51% busy (19.4cyc/MFMA/SIMD x 64/fold-pair), VALU
// ~17%, residual = per-wave dep stalls (insensitive to stage-pipelining,
// de-phasing, decorrelation); 2 waves/SIMD reg-capped (128V + 128A).
// =====================================================================
#define MST0(OUT, BN) \
  OUT##0 = MFMA(tb0_0, BN, zz4); OUT##1 = MFMA(tb1_0, BN, zz4); \
  OUT##2 = MFMA(tb2_0, BN, zz4); OUT##3 = MFMA(tb3_0, BN, zz4); \
  OUT##4 = MFMA(tb4_0, BN, zz4); OUT##5 = MFMA(tb5_0, BN, zz4); \
  OUT##6 = MFMA(tb6_0, BN, zz4); OUT##7 = MFMA(tb7_0, BN, zz4);
#define MSTA(OUT, BN, ks) \
  OUT##0 = MFMA(tb0_##ks, BN, OUT##0); OUT##1 = MFMA(tb1_##ks, BN, OUT##1); \
  OUT##2 = MFMA(tb2_##ks, BN, OUT##2); OUT##3 = MFMA(tb3_##ks, BN, OUT##3); \
  OUT##4 = MFMA(tb4_##ks, BN, OUT##4); OUT##5 = MFMA(tb5_##ks, BN, OUT##5); \
  OUT##6 = MFMA(tb6_##ks, BN, OUT##6); OUT##7 = MFMA(tb7_##ks, BN, OUT##7);

#define PKPAIR(CCA, CCB, QA, QB, DOUT) { \
  float f0 = bflo(QA.x) * rs, f1 = bfhi(QA.x) * rs; \
  float f2 = bflo(QA.y) * rs, f3 = bfhi(QA.y) * rs; \
  float s0 = CCA.x * f0, s1 = CCA.y * f1, s2 = CCA.z * f2, s3 = CCA.w * f3; \
  fm = fmaxf(fm, fmaxf(fmaxf(s0, s1), fmaxf(s2, s3))); \
  uint p0, p1, p2, p3; \
  asm("v_cvt_pk_bf16_f32 %0, %1, %2" : "=v"(p0) : "v"(s0), "v"(s1)); \
  asm("v_cvt_pk_bf16_f32 %0, %1, %2" : "=v"(p1) : "v"(s2), "v"(s3)); \
  float g0 = bflo(QB.x) * rs, g1 = bfhi(QB.x) * rs; \
  float g2 = bflo(QB.y) * rs, g3 = bfhi(QB.y) * rs; \
  float t0 = CCB.x * g0, t1 = CCB.y * g1, t2 = CCB.z * g2, t3 = CCB.w * g3; \
  fm = fmaxf(fm, fmaxf(fmaxf(t0, t1), fmaxf(t2, t3))); \
  asm("v_cvt_pk_bf16_f32 %0, %1, %2" : "=v"(p2) : "v"(t0), "v"(t1)); \
  asm("v_cvt_pk_bf16_f32 %0, %1, %2" : "=v"(p3) : "v"(t2), "v"(t3)); \
  DOUT.x = p0; DOUT.y = p1; DOUT.z = p2; DOUT.w = p3; }

#define PKPAIR_NR(CCA, CCB, QA, QB, DOUT) { \
  float s0 = CCA.x * bflo(QA.x), s1 = CCA.y * bfhi(QA.x); \
  float s2 = CCA.z * bflo(QA.y), s3 = CCA.w * bfhi(QA.y); \
  uint p0, p1, p2, p3; \
  asm("v_cvt_pk_bf16_f32 %0, %1, %2" : "=v"(p0) : "v"(s0), "v"(s1)); \
  asm("v_cvt_pk_bf16_f32 %0, %1, %2" : "=v"(p1) : "v"(s2), "v"(s3)); \
  float t0 = CCB.x * bflo(QB.x), t1 = CCB.y * bfhi(QB.x); \
  float t2 = CCB.z * bflo(QB.y), t3 = CCB.w * bfhi(QB.y); \
  asm("v_cvt_pk_bf16_f32 %0, %1, %2" : "=v"(p2) : "v"(t0), "v"(t1)); \
  asm("v_cvt_pk_bf16_f32 %0, %1, %2" : "=v"(p3) : "v"(t2), "v"(t3)); \
  DOUT.x = p0; DOUT.y = p1; DOUT.z = p2; DOUT.w = p3; }

#define QLD(dst, tk, i) dst = *(const uint2*)(qtbl + ((size_t)(tk) << 6) + 8 * (i) + 2 * quad);

#define QRELOAD(Q, TKREG, FBASE) \
  QLD(Q##0, TKREG, 0) QLD(Q##1, TKREG, 1) QLD(Q##2, TKREG, 2) QLD(Q##3, TKREG, 3) \
  QLD(Q##4, TKREG, 4) QLD(Q##5, TKREG, 5) QLD(Q##6, TKREG, 6) QLD(Q##7, TKREG, 7) \
  { int fi_ = (FBASE) + 4; if (fi_ > 511) fi_ = 511; TKREG = xseg[fi_]; }

#define SLOT_RS(CIN, COUT, Q, TKREG, FBASE) { \
  rs = 1.0f / fmA;  llacc += __log2f(fmA); \
  float fm = 0.f; \
  PKPAIR(CIN##0, CIN##1, Q##0, Q##1, Bs0) \
  MST0(COUT, Bs0) \
  PKPAIR(CIN##2, CIN##3, Q##2, Q##3, Bs1) \
  MSTA(COUT, Bs1, 1) \
  PKPAIR(CIN##4, CIN##5, Q##4, Q##5, Bs2) \
  MSTA(COUT, Bs2, 2) \
  PKPAIR(CIN##6, CIN##7, Q##6, Q##7, Bs3) \
  MSTA(COUT, Bs3, 3) \
  QRELOAD(Q, TKREG, FBASE) \
  fm = fmaxf(fm, __shfl_xor(fm, 16, 64)); \
  fm = fmaxf(fm, __shfl_xor(fm, 32, 64)); \
  fmA = fmaxf(fm, 1e-33f); \
}

#define SLOT_NR(CIN, COUT, Q, TKREG, FBASE) { \
  PKPAIR_NR(CIN##0, CIN##1, Q##0, Q##1, Bs0) \
  MST0(COUT, Bs0) \
  PKPAIR_NR(CIN##2, CIN##3, Q##2, Q##3, Bs1) \
  MSTA(COUT, Bs1, 1) \
  PKPAIR_NR(CIN##4, CIN##5, Q##4, Q##5, Bs2) \
  MSTA(COUT, Bs2, 2) \
  PKPAIR_NR(CIN##6, CIN##7, Q##6, Q##7, Bs3) \
  MSTA(COUT, Bs3, 3) \
  QRELOAD(Q, TKREG, FBASE) \
}

__global__ __attribute__((amdgpu_flat_work_group_size(512, 512), amdgpu_waves_per_eu(2)))
void k_seg(const int* __restrict__ x, const uint* __restrict__ Tcol,
           const uint* __restrict__ qtbl, uint* __restrict__ Pst,
           float* __restrict__ LLseg) {
  int tid = threadIdx.x;
  int wv = tid >> 6, l = tid & 63, c = l & 15, quad = l >> 4;
  int blk = blockIdx.x;
  const int* xseg = x + (size_t)(blk >> 3) * 4096 + (size_t)(blk & 7) * 512;

  #define DECLB(nt, ks) ui4v tb##nt##_##ks;
  REPB(DECLB)
  {
    #define LOADB(nt, ks) { \
      const uint2* t2_ = (const uint2*)(Tcol + (size_t)(16 * (nt) + c) * 64 + 16 * (ks) + 2 * quad); \
      uint2 lo_ = t2_[0], hi_ = t2_[4]; \
      tb##nt##_##ks.x = lo_.x; tb##nt##_##ks.y = lo_.y; \
      tb##nt##_##ks.z = hi_.x; tb##nt##_##ks.w = hi_.y; }
    REPB(LOADB)
    #define PINB(nt, ks) asm volatile("" : "+a"(tb##nt##_##ks));
    REPB(PINB)
  }

  ui4v Bs0, Bs1, Bs2, Bs3;
  {
    uint iv = (quad == (c >> 2)) ? (0x3F80u << (16 * (c & 1))) : 0u;
    int dsel = ((c >> 1) & 1) + 2 * (wv & 1);
    int kssel = wv >> 1;
    Bs0.x = (kssel == 0 && dsel == 0) ? iv : 0u;
    Bs0.y = (kssel == 0 && dsel == 1) ? iv : 0u;
    Bs0.z = (kssel == 0 && dsel == 2) ? iv : 0u;
    Bs0.w = (kssel == 0 && dsel == 3) ? iv : 0u;
    Bs1.x = (kssel == 1 && dsel == 0) ? iv : 0u;
    Bs1.y = (kssel == 1 && dsel == 1) ? iv : 0u;
    Bs1.z = (kssel == 1 && dsel == 2) ? iv : 0u;
    Bs1.w = (kssel == 1 && dsel == 3) ? iv : 0u;
    Bs2.x = (kssel == 2 && dsel == 0) ? iv : 0u;
    Bs2.y = (kssel == 2 && dsel == 1) ? iv : 0u;
    Bs2.z = (kssel == 2 && dsel == 2) ? iv : 0u;
    Bs2.w = (kssel == 2 && dsel == 3) ? iv : 0u;
    Bs3.x = (kssel == 3 && dsel == 0) ? iv : 0u;
    Bs3.y = (kssel == 3 && dsel == 1) ? iv : 0u;
    Bs3.z = (kssel == 3 && dsel == 2) ? iv : 0u;
    Bs3.w = (kssel == 3 && dsel == 3) ? iv : 0u;
  }

  float rs = 1.0f, llacc = 0.0f, fmA = 1.0f;
  fx4 zz4; zz4.x = 0.f; zz4.y = 0.f; zz4.z = 0.f; zz4.w = 0.f;

  fx4 cA0, cA1, cA2, cA3, cA4, cA5, cA6, cA7;
  fx4 cB0, cB1, cB2, cB3, cB4, cB5, cB6, cB7;

  int tk0 = xseg[0], tk1 = xseg[1];
  int tkA = xseg[2], tkB = xseg[3];
  uint2 qc0, qc1, qc2, qc3, qc4, qc5, qc6, qc7;
  uint2 qn0, qn1, qn2, qn3, qn4, qn5, qn6, qn7;
  QLD(qc0, tk0, 0) QLD(qc1, tk0, 1) QLD(qc2, tk0, 2) QLD(qc3, tk0, 3)
  QLD(qc4, tk0, 4) QLD(qc5, tk0, 5) QLD(qc6, tk0, 6) QLD(qc7, tk0, 7)
  QLD(qn0, tk1, 0) QLD(qn1, tk1, 1) QLD(qn2, tk1, 2) QLD(qn3, tk1, 3)
  QLD(qn4, tk1, 4) QLD(qn5, tk1, 5) QLD(qn6, tk1, 6) QLD(qn7, tk1, 7)

  MST0(cA, Bs0) MSTA(cA, Bs1, 1) MSTA(cA, Bs2, 2) MSTA(cA, Bs3, 3)

  if (wv & 1) __builtin_amdgcn_s_sleep(8);

  for (int f4 = 0; f4 < 128; ++f4) {
    int f = f4 * 4;
    SLOT_RS(cA, cB, qc, tkA, f)
    SLOT_NR(cB, cA, qn, tkB, f + 1)
    SLOT_NR(cA, cB, qc, tkA, f + 2)
    SLOT_NR(cB, cA, qn, tkB, f + 3)
  }

  size_t pb = (size_t)blk * 8192 + (size_t)(16 * wv + c) * 64;
  uint2 st;
  st.x = Bs0.x; st.y = Bs0.y; *(uint2*)(Pst + pb +  0 + 2 * quad) = st;
  st.x = Bs0.z; st.y = Bs0.w; *(uint2*)(Pst + pb +  8 + 2 * quad) = st;
  st.x = Bs1.x; st.y = Bs1.y; *(uint2*)(Pst + pb + 16 + 2 * quad) = st;
  st.x = Bs1.z; st.y = Bs1.w; *(uint2*)(Pst + pb + 24 + 2 * quad) = st;
  st.x = Bs2.x; st.y = Bs2.y; *(uint2*)(Pst + pb + 32 + 2 * quad) = st;
  st.x = Bs2.z; st.y = Bs2.w; *(uint2*)(Pst + pb + 40 + 2 * quad) = st;
  st.x = Bs3.x; st.y = Bs3.y; *(uint2*)(Pst + pb + 48 + 2 * quad) = st;
  st.x = Bs3.z; st.y = Bs3.w; *(uint2*)(Pst + pb + 56 + 2 * quad) = st;
  if (quad == 0)
    LLseg[(size_t)blk * 128 + 16 * wv + c] = llacc * 0.6931471805599453f;
}

// =====================================================================
// PHASE 2 (8-wave, absorbs Emax token-sum): per chain, alpha0 -> fold 8
// segment matrices.
// =====================================================================
__global__ __launch_bounds__(512, 1) void k_comb(
    const float* __restrict__ start_w, const float* __restrict__ start_b,
    const uint* __restrict__ Pst, const float* __restrict__ LLseg,
    const int* __restrict__ x, const float* __restrict__ Emax,
    float* __restrict__ chainLL) {
  __shared__ uint al[64] __attribute__((aligned(16)));
  __shared__ float2 part[8][64];
  __shared__ float esum[8];
  int n = blockIdx.x, tid = threadIdx.x;
  int wv = tid >> 6, l = tid & 63;
  const int* xrow = x + (size_t)n * 4096;

  float es = 0.f;
  #pragma unroll
  for (int t = 0; t < 8; ++t) es += Emax[xrow[tid + 512 * t]];
  #pragma unroll
  for (int mk = 1; mk < 64; mk <<= 1) es += __shfl_xor(es, mk, 64);
  if (l == 0) esum[wv] = es;

  float p0 = 0.f, p1 = 0.f, LLacc = 0.f;
  if (wv == 0) {
    float a0i = start_w[2 * l] + start_b[2 * l];
    float a1i = start_w[2 * l + 1] + start_b[2 * l + 1];
    float m = fmaxf(a0i, a1i);
    #pragma unroll
    for (int s = 1; s < 64; s <<= 1) m = fmaxf(m, __shfl_xor(m, s, 64));
    p0 = __expf(a0i - m); p1 = __expf(a1i - m);
    float tot = p0 + p1;
    #pragma unroll
    for (int s = 1; s < 64; s <<= 1) tot += __shfl_xor(tot, s, 64);
    LLacc = m + __logf(tot);
    float inv = 1.0f / tot;
    p0 *= inv; p1 *= inv;
  }
  const uint4_a* u4 = (const uint4_a*)al;

  for (int s = 0; s < 8; ++s) {
    float g = 0.f;
    if (wv == 0) {
      float La = LLseg[(size_t)(n * 8 + s) * 128 + 2 * l];
      float Lb = LLseg[(size_t)(n * 8 + s) * 128 + 2 * l + 1];
      g = fmaxf(La, Lb);
      #pragma unroll
      for (int sh = 1; sh < 64; sh <<= 1) g = fmaxf(g, __shfl_xor(g, sh, 64));
      al[l] = bfpack(p0 * __expf(La - g), p1 * __expf(Lb - g));
    }
    __syncthreads();

    const uint* pb = Pst + (size_t)(n * 8 + s) * 8192;
    float o0 = 0.f, o1 = 0.f;
    #pragma unroll
    for (int ii = 0; ii < 2; ++ii) {
      int i = 2 * wv + ii;
      uint4 uu = u4[i];
      #pragma unroll
      for (int d = 0; d < 4; ++d) {
        uint ad = (d == 0) ? uu.x : (d == 1) ? uu.y : (d == 2) ? uu.z : uu.w;
        uint P0 = pb[(8 * i + 2 * d) * 64 + l];
        uint P1 = pb[(8 * i + 2 * d + 1) * 64 + l];
        float alo = bflo(ad), ahi = bfhi(ad);
        o0 = fmaf(alo, bflo(P0), o0); o0 = fmaf(ahi, bflo(P1), o0);
        o1 = fmaf(alo, bfhi(P0), o1); o1 = fmaf(ahi, bfhi(P1), o1);
      }
    }
    part[wv][l] = make_float2(o0, o1);
    __syncthreads();

    if (wv == 0) {
      float2 x0 = part[0][l], x1 = part[1][l], x2 = part[2][l], x3 = part[3][l];
      float2 x4 = part[4][l], x5 = part[5][l], x6 = part[6][l], x7 = part[7][l];
      float s0 = ((x0.x + x1.x) + (x2.x + x3.x)) + ((x4.x + x5.x) + (x6.x + x7.x));
      float s1 = ((x0.y + x1.y) + (x2.y + x3.y)) + ((x4.y + x5.y) + (x6.y + x7.y));
      float tt = s0 + s1;
      #pragma unroll
      for (int sh = 1; sh < 64; sh <<= 1) tt += __shfl_xor(tt, sh, 64);
      LLacc += g + __logf(tt);
      float it = 1.0f / tt;
      p0 = s0 * it; p1 = s1 * it;
    }
  }
  if (tid == 0) {
    float et = ((esum[0] + esum[1]) + (esum[2] + esum[3])) +
               ((esum[4] + esum[5]) + (esum[6] + esum[7]));
    chainLL[n] = LLacc + et;
  }
}

// =====================================================================
// FALLBACK: sequential scan, 4 waves per chain — used if ws too small
// =====================================================================
#define RLU(i) ((uint)__builtin_amdgcn_readlane((int)ud, rbase + (i)))
#if HAVE_BFDOT
#define DOTS \
  uint u0=RLU(0),u1=RLU(1),u2=RLU(2),u3=RLU(3),u4=RLU(4),u5=RLU(5),u6=RLU(6),u7=RLU(7), \
       u8=RLU(8),u9=RLU(9),u10=RLU(10),u11=RLU(11),u12=RLU(12),u13=RLU(13),u14=RLU(14),u15=RLU(15); \
  float A0 = dot2bf(u0, tA0.x, 0.f), A1 = dot2bf(u1, tA0.y, 0.f); \
  float A2 = dot2bf(u2, tA0.z, 0.f), A3 = dot2bf(u3, tA0.w, 0.f); \
  float B0 = dot2bf(u0, tB0.x, 0.f), B1 = dot2bf(u1, tB0.y, 0.f); \
  float B2 = dot2bf(u2, tB0.z, 0.f), B3 = dot2bf(u3, tB0.w, 0.f); \
  A0 = dot2bf(u4, tA1.x, A0); A1 = dot2bf(u5, tA1.y, A1); \
  A2 = dot2bf(u6, tA1.z, A2); A3 = dot2bf(u7, tA1.w, A3); \
  B0 = dot2bf(u4, tB1.x, B0); B1 = dot2bf(u5, tB1.y, B1); \
  B2 = dot2bf(u6, tB1.z, B2); B3 = dot2bf(u7, tB1.w, B3); \
  A0 = dot2bf(u8, tA2.x, A0); A1 = dot2bf(u9, tA2.y, A1); \
  A2 = dot2bf(u10, tA2.z, A2); A3 = dot2bf(u11, tA2.w, A3); \
  B0 = dot2bf(u8, tB2.x, B0); B1 = dot2bf(u9, tB2.y, B1); \
  B2 = dot2bf(u10, tB2.z, B2); B3 = dot2bf(u11, tB2.w, B3); \
  A0 = dot2bf(u12, tA3.x, A0); A1 = dot2bf(u13, tA3.y, A1); \
  A2 = dot2bf(u14, tA3.z, A2); A3 = dot2bf(u15, tA3.w, A3); \
  B0 = dot2bf(u12, tB3.x, B0); B1 = dot2bf(u13, tB3.y, B1); \
  B2 = dot2bf(u14, tB3.z, B2); B3 = dot2bf(u15, tB3.w, B3); \
  float Asum = (A0 + A1) + (A2 + A3), Bsum = (B0 + B1) + (B2 + B3);
#else
#define ACC2(i, AA, BB) { uint tu = RLU(i); float lo = bflo(tu), hi = bfhi(tu); \
  AA += lo * fa##i.x; AA += hi * fa##i.y; BB += lo * fb##i.x; BB += hi * fb##i.y; }
#define DOTS \
  float A0 = 0.f, A1 = 0.f, A2 = 0.f, A3 = 0.f; \
  float B0 = 0.f, B1 = 0.f, B2 = 0.f, B3 = 0.f; \
  ACC2(0, A0, B0) ACC2(1, A1, B1) ACC2(2, A2, B2) ACC2(3, A3, B3) \
  ACC2(4, A0, B0) ACC2(5, A1, B1) ACC2(6, A2, B2) ACC2(7, A3, B3) \
  ACC2(8, A0, B0) ACC2(9, A1, B1) ACC2(10, A2, B2) ACC2(11, A3, B3) \
  ACC2(12, A0, B0) ACC2(13, A1, B1) ACC2(14, A2, B2) ACC2(15, A3, B3) \
  float Asum = (A0 + A1) + (A2 + A3), Bsum = (B0 + B1) + (B2 + B3);
#endif

#define STEPF(j, p) { \
  DOTS \
  *(float2*)&partLDS[(p) * 640 + l * 10 + 2 * wv] = make_float2(Asum, Bsum); \
  asm volatile("s_waitcnt lgkmcnt(0)\ns_barrier" ::: "memory"); \
  const float2* pr = (const float2*)&partLDS[(p) * 640 + l * 10]; \
  float2 x0 = pr[0], x1 = pr[1], x2 = pr[2], x3 = pr[3]; \
  float s0 = (x0.x + x1.x) + (x2.x + x3.x); \
  float s1 = (x0.y + x1.y) + (x2.y + x3.y); \
  float nu0 = s0 * bflo(qc##j), nu1 = s1 * bfhi(qc##j); \
  qc##j = qtbl[(size_t)tk##j * 64 + l]; \
  tk##j = xrow[(tbase + (j) + 16) & 4095]; \
  if ((j) == 7) { \
    float tt = nu0 + nu1; \
    for (int s = 1; s < 64; s <<= 1) tt += __shfl_xor(tt, s, 64); \
    LLacc += __logf(tt); \
    float it = 1.0f / tt; nu0 *= it; nu1 *= it; \
  } \
  ud = bfpack(nu0, nu1); }

__global__ __launch_bounds__(256, 1) void k_chain(const int* __restrict__ x,
    const float* __restrict__ start_w, const float* __restrict__ start_b,
    const uint* __restrict__ Tcol, const uint* __restrict__ qtbl,
    float* __restrict__ chainLL) {
  __shared__ float partLDS[1280];
  int n = blockIdx.x;
  int l = threadIdx.x & 63;
  int wv = __builtin_amdgcn_readfirstlane((int)(threadIdx.x >> 6));
  int rbase = wv * 16;
  const int* xrow = x + (size_t)n * 4096;

  const uint4* ca = (const uint4*)(Tcol + (2 * l) * 64 + rbase);
  const uint4* cb = (const uint4*)(Tcol + (2 * l + 1) * 64 + rbase);
  uint4 tA0 = ca[0], tA1 = ca[1], tA2 = ca[2], tA3 = ca[3];
  uint4 tB0 = cb[0], tB1 = cb[1], tB2 = cb[2], tB3 = cb[3];
#if !HAVE_BFDOT
  float2 fa0 = make_float2(bflo(tA0.x), bfhi(tA0.x)), fa1 = make_float2(bflo(tA0.y), bfhi(tA0.y));
  float2 fa2 = make_float2(bflo(tA0.z), bfhi(tA0.z)), fa3 = make_float2(bflo(tA0.w), bfhi(tA0.w));
  float2 fa4 = make_float2(bflo(tA1.x), bfhi(tA1.x)), fa5 = make_float2(bflo(tA1.y), bfhi(tA1.y));
  float2 fa6 = make_float2(bflo(tA1.z), bfhi(tA1.z)), fa7 = make_float2(bflo(tA1.w), bfhi(tA1.w));
  float2 fa8 = make_float2(bflo(tA2.x), bfhi(tA2.x)), fa9 = make_float2(bflo(tA2.y), bfhi(tA2.y));
  float2 fa10 = make_float2(bflo(tA2.z), bfhi(tA2.z)), fa11 = make_float2(bflo(tA2.w), bfhi(tA2.w));
  float2 fa12 = make_float2(bflo(tA3.x), bfhi(tA3.x)), fa13 = make_float2(bflo(tA3.y), bfhi(tA3.y));
  float2 fa14 = make_float2(bflo(tA3.z), bfhi(tA3.z)), fa15 = make_float2(bflo(tA3.w), bfhi(tA3.w));
  float2 fb0 = make_float2(bflo(tB0.x), bfhi(tB0.x)), fb1 = make_float2(bflo(tB0.y), bfhi(tB0.y));
  float2 fb2 = make_float2(bflo(tB0.z), bfhi(tB0.z)), fb3 = make_float2(bflo(tB0.w), bfhi(tB0.w));
  float2 fb4 = make_float2(bflo(tB1.x), bfhi(tB1.x)), fb5 = make_float2(bflo(tB1.y), bfhi(tB1.y));
  float2 fb6 = make_float2(bflo(tB1.z), bfhi(tB1.z)), fb7 = make_float2(bflo(tB1.w), bfhi(tB1.w));
  float2 fb8 = make_float2(bflo(tB2.x), bfhi(tB2.x)), fb9 = make_float2(bflo(tB2.y), bfhi(tB2.y));
  float2 fb10 = make_float2(bflo(tB2.z), bfhi(tB2.z)), fb11 = make_float2(bflo(tB2.w), bfhi(tB2.w));
  float2 fb12 = make_float2(bflo(tB3.x), bfhi(tB3.x)), fb13 = make_float2(bflo(tB3.y), bfhi(tB3.y));
  float2 fb14 = make_float2(bflo(tB3.z), bfhi(tB3.z)), fb15 = make_float2(bflo(tB3.w), bfhi(tB3.w));
#endif

  float a0i = start_w[2 * l] + start_b[2 * l];
  float a1i = start_w[2 * l + 1] + start_b[2 * l + 1];
  float m = fmaxf(a0i, a1i);
  #pragma unroll
  for (int s = 1; s < 64; s <<= 1) m = fmaxf(m, __shfl_xor(m, s, 64));
  float p0 = __expf(a0i - m), p1 = __expf(a1i - m);
  float tot = p0 + p1;
  #pragma unroll
  for (int s = 1; s < 64; s <<= 1) tot += __shfl_xor(tot, s, 64);
  float LLacc = m + __logf(tot);
  float inv = 1.0f / tot;
  uint ud = bfpack(p0 * inv, p1 * inv);

  uint qc0 = qtbl[(size_t)xrow[0] * 64 + l], qc1 = qtbl[(size_t)xrow[1] * 64 + l];
  uint qc2 = qtbl[(size_t)xrow[2] * 64 + l], qc3 = qtbl[(size_t)xrow[3] * 64 + l];
  uint qc4 = qtbl[(size_t)xrow[4] * 64 + l], qc5 = qtbl[(size_t)xrow[5] * 64 + l];
  uint qc6 = qtbl[(size_t)xrow[6] * 64 + l], qc7 = qtbl[(size_t)xrow[7] * 64 + l];
  int tk0 = xrow[8],  tk1 = xrow[9],  tk2 = xrow[10], tk3 = xrow[11];
  int tk4 = xrow[12], tk5 = xrow[13], tk6 = xrow[14], tk7 = xrow[15];

  for (int t8 = 0; t8 < 512; ++t8) {
    int tbase = t8 * 8;
    STEPF(0, 0) STEPF(1, 1) STEPF(2, 0) STEPF(3, 1)
    STEPF(4, 0) STEPF(5, 1) STEPF(6, 0) STEPF(7, 1)
  }
  if (l == 0 && wv == 0) chainLL[n] = LLacc;
}

// ---------- K4a: sum of Emax over all tokens (fallback path only) ----------
__global__ __launch_bounds__(256) void k_emaxsum(const int* __restrict__ x,
    const float* __restrict__ Emax, float* __restrict__ sumE, int NT) {
  int idx = blockIdx.x * 256 + threadIdx.x;
  float s = 0.f;
  for (; idx < NT; idx += 128 * 256) s += Emax[x[idx]];
  #pragma unroll
  for (int mk = 1; mk < 64; mk <<= 1) s += __shfl_xor(s, mk, 64);
  if ((threadIdx.x & 63) == 0) atomicAdd(sumE, s);
}

// ---------- K4b: final scalar (sumE = 0 on main path) ----------
__global__ void k_final(const float* __restrict__ chainLL, const float* __restrict__ sumE,
                        float* __restrict__ out, int N) {
  int l = threadIdx.x;
  float v = (l < N) ? chainLL[l] : 0.f;
  #pragma unroll
  for (int mk = 1; mk < 64; mk <<= 1) v += __shfl_xor(v, mk, 64);
  if (l == 0) out[0] = -(v + sumE[0]) / (float)N;
}

extern "C" void kernel_launch(void* const* d_in, const int* in_sizes, int n_in,
                              void* d_out, int out_size, void* d_ws, size_t ws_size,
                              hipStream_t stream) {
  if (n_in < 6) return;
  const int*   x       = (const int*)d_in[0];
  const float* start_w = (const float*)d_in[1];
  const float* start_b = (const float*)d_in[2];
  const float* trans_w = (const float*)d_in[3];
  const float* emb_w   = (const float*)d_in[4];
  const float* vocab_w = (const float*)d_in[5];
  int NT = in_sizes[0];
  int N  = NT / 4096;
  int V  = in_sizes[5] / 128;

  char* ws = (char*)d_ws;
  float* S_glob  = (float*)(ws + 0);        // 128 f
  float* sumE    = (float*)(ws + 512);      // 1 f (stays 0 on main path)
  float* chainLL = (float*)(ws + 768);      // N f
  uint*  Tcol    = (uint*)(ws + 1024);      // 32 KB (ends 33792)
  uint*  Ecol    = (uint*)(ws + 36864);     // 32 KB (ends 69632)
  float* Emax    = (float*)(ws + 73728);    // V floats
  size_t qtbl_off = 73728 + (size_t)V * 4;
  qtbl_off = (qtbl_off + 255) & ~(size_t)255;
  uint*  qtbl    = (uint*)(ws + qtbl_off);  // V*64 dwords
  size_t pst_off = qtbl_off + (size_t)V * 256;
  uint*  Pst     = (uint*)(ws + pst_off);   // N*8*8192 dwords
  size_t llseg_off = pst_off + (size_t)N * 8 * 8192 * 4;
  float* LLseg   = (float*)(ws + llseg_off);  // N*8*128 floats
  size_t need    = llseg_off + (size_t)N * 8 * 128 * 4 + 64;

  hipMemsetAsync(d_ws, 0, 1024, stream);
  k_prep<<<dim3(128), dim3(128), 0, stream>>>(trans_w, emb_w, Tcol, Ecol);
  k_logits<<<dim3((V + 255) / 256), dim3(256), 0, stream>>>(vocab_w, Ecol, qtbl, S_glob, V);
  k_qtab<<<dim3((V + 15) / 16), dim3(256), 0, stream>>>(qtbl, S_glob, Emax, V);
  if (ws_size >= need) {
    k_seg<<<dim3(N * 8), dim3(512), 0, stream>>>(x, Tcol, qtbl, Pst, LLseg);
    k_comb<<<dim3(N), dim3(512), 0, stream>>>(start_w, start_b, Pst, LLseg, x, Emax, chainLL);
  } else {
    k_chain<<<dim3(N), dim3(256), 0, stream>>>(x, start_w, start_b, Tcol, qtbl, chainLL);
    k_emaxsum<<<dim3(128), dim3(256), 0, stream>>>(x, Emax, sumE, NT);
  }
  k_final<<<dim3(1), dim3(64), 0, stream>>>(chainLL, sumE, (float*)d_out, N);
}